// Round 8
// baseline (491.117 us; speedup 1.0000x reference)
//
#include <hip/hip_runtime.h>
#include <hip/hip_bf16.h>
#include <stdint.h>

#define B_ 8
#define P_ 2048
#define K_ 20
#define N_ (B_*P_)     // 16384
#define M_ (B_*K_)     // 160
#define C 128
#define E_ (N_*K_)     // 327680
#define EPS_ 1e-5f

typedef unsigned short u16;
typedef unsigned int u32;
typedef __attribute__((ext_vector_type(8))) short short8;
typedef __attribute__((ext_vector_type(4))) float floatx4;

__device__ __forceinline__ float bf2f(u16 u){
    union { u32 i; float f; } v; v.i = ((u32)u) << 16; return v.f;
}
__device__ __forceinline__ u16 f2bf(float f){
    union { float f; u32 i; } v; v.f = f;
    u32 r = ((v.i >> 16) & 1u) + 0x7fffu;
    return (u16)((v.i + r) >> 16);
}
__device__ __forceinline__ u32 pkbf(float a, float b){
    union { __hip_bfloat162 h; u32 u; } cv;
    cv.h = __float22bfloat162_rn(make_float2(a, b));
    return cv.u;
}

// ---------------------------------------------------------------------------
// prep: CqT = (aW1@Wq)^T [64,128], CkT = (aW1@Wk)^T, dq = aW1@bq + ab1,
//       dk = aW1@bk, WvT [64,128], frag-major bf16 copies of pW2, aW1, aW2.
// grid 69 x 256
__global__ __launch_bounds__(256)
void prep_weights(const float* __restrict__ Wq, const float* __restrict__ bq,
                  const float* __restrict__ Wk, const float* __restrict__ bk,
                  const float* __restrict__ aW1, const float* __restrict__ ab1,
                  const float* __restrict__ pW2, const float* __restrict__ aW2,
                  const float* __restrict__ Wv,
                  float* __restrict__ CqT, float* __restrict__ CkT,
                  float* __restrict__ dq, float* __restrict__ dk,
                  float* __restrict__ WvT,
                  u16* __restrict__ Wb0, u16* __restrict__ Wb1, u16* __restrict__ Wb2)
{
    int tid = threadIdx.x, blk = blockIdx.x;
    if (blk < 32) {
        int idx = blk*256 + tid; int o = idx >> 6, i = idx & 63;
        float s = 0.f;
        for (int cc = 0; cc < 128; ++cc) s = fmaf(aW1[o*128+cc], Wq[cc*64+i], s);
        CqT[i*128 + o] = s;
    } else if (blk < 64) {
        int idx = (blk-32)*256 + tid; int o = idx >> 6, i = idx & 63;
        float s = 0.f;
        for (int cc = 0; cc < 128; ++cc) s = fmaf(aW1[o*128+cc], Wk[cc*64+i], s);
        CkT[i*128 + o] = s;
    } else if (blk == 64) {
        if (tid < 128) {
            float s = ab1[tid];
            for (int cc = 0; cc < 128; ++cc) s = fmaf(aW1[tid*128+cc], bq[cc], s);
            dq[tid] = s;
        } else {
            int o = tid - 128;
            float s = 0.f;
            for (int cc = 0; cc < 128; ++cc) s = fmaf(aW1[o*128+cc], bk[cc], s);
            dk[o] = s;
        }
    } else if (blk == 68) {
        for (int idx = tid; idx < 8192; idx += 256) {
            int o = idx >> 6, i = idx & 63;
            WvT[i*128 + o] = Wv[idx];
        }
    } else {
        // frag-major remap: slot s = (ct*4+ks)*64 + lane, 8 u16 per slot.
        const float* src = (blk == 65) ? pW2 : (blk == 66) ? aW1 : aW2;
        u16* dst = (blk == 65) ? Wb0 : (blk == 66) ? Wb1 : Wb2;
        for (int s = tid; s < 2048; s += 256) {
            int ln = s & 63, ks = (s >> 6) & 3, ct = s >> 8;
            int Ls = ln & 15, qs = ln >> 4;
            const float* sp = src + (ct*16+Ls)*C + ks*32 + qs*8;
            #pragma unroll
            for (int j = 0; j < 8; ++j) dst[s*8+j] = f2bf(sp[j]);
        }
    }
}

// ---------------------------------------------------------------------------
// knn + kernel-weighted scatter into gacc[m][68] + per-graph pos moments.
// grid 256 x 256
__global__ __launch_bounds__(256)
void knn_scatter(const float* __restrict__ pos, const float* __restrict__ x,
                 const int* __restrict__ fps_idx, float* __restrict__ gacc,
                 float* __restrict__ posmom)
{
    __shared__ float fpos[K_][3];
    __shared__ float accL[K_*68];
    __shared__ int   skb[64];
    __shared__ float sek[64];
    int tid = threadIdx.x;
    int b = blockIdx.x >> 5;              // 32 blocks per graph
    if (tid < K_*3) {
        int k = tid / 3, d = tid - k*3;
        fpos[k][d] = pos[fps_idx[b*K_+k]*3 + d];
    }
    for (int i = tid; i < K_*68; i += 256) accL[i] = 0.f;
    __syncthreads();

    int wbase = blockIdx.x*64;
    if (tid < 64) {
        int p = wbase + tid;
        float px = pos[p*3], py = pos[p*3+1], pz = pos[p*3+2];
        float best = 1e30f; int kb = 0;
        #pragma unroll
        for (int k = 0; k < K_; ++k) {
            float dx = px - fpos[k][0], dy = py - fpos[k][1], dz = pz - fpos[k][2];
            float d2 = dx*dx + dy*dy + dz*dz;
            if (d2 < best) { best = d2; kb = k; }   // strict <: argmin keeps first
        }
        float ek = 1.0f / (1.0f + 5.0f*best);
        skb[tid] = kb; sek[tid] = ek;
        atomicAdd(&accL[kb*68 + 0], 1.0f);
        atomicAdd(&accL[kb*68 + 1], ek*px);
        atomicAdd(&accL[kb*68 + 2], ek*py);
        atomicAdd(&accL[kb*68 + 3], ek*pz);

        float mom[9] = {px,py,pz, px*px,px*py,px*pz, py*py,py*pz, pz*pz};
        #pragma unroll
        for (int i = 0; i < 9; ++i) {
            float v = mom[i];
            v += __shfl_xor(v,32); v += __shfl_xor(v,16); v += __shfl_xor(v,8);
            v += __shfl_xor(v,4);  v += __shfl_xor(v,2);  v += __shfl_xor(v,1);
            mom[i] = v;
        }
        if (tid == 0) {
            #pragma unroll
            for (int i = 0; i < 9; ++i) atomicAdd(&posmom[b*9+i], mom[i]);
        }
    }
    __syncthreads();

    int w = tid >> 6, lane = tid & 63;
    #pragma unroll
    for (int jj = 0; jj < 16; ++jj) {
        int j = w*16 + jj;
        int   kbj = skb[j];
        float ekj = sek[j];
        float xvv = x[(size_t)(wbase+j)*64 + lane];
        atomicAdd(&accL[kbj*68 + 4 + lane], ekj*xvv);
    }
    __syncthreads();
    for (int i = tid; i < K_*68; i += 256)
        atomicAdd(&gacc[b*K_*68 + i], accL[i]);
}

// ---------------------------------------------------------------------------
// proj_m + fps divide: divides gacc row m in place (for bn1_prep & gemm1),
// then Ak2[m] = Ck@fps_x + dk ; xv[m] = Wv@fps_x + bv. grid 160 x 128
__global__ __launch_bounds__(128)
void proj_m(float* __restrict__ gacc, const float* __restrict__ CkT,
            const float* __restrict__ dk, const float* __restrict__ WvT,
            const float* __restrict__ bv, float* __restrict__ Ak2,
            float* __restrict__ xv)
{
    __shared__ float sfx[68];
    int m = blockIdx.x, o = threadIdx.x;
    if (o < 68) {
        float c = gacc[m*68];
        float inv = 1.0f / (c > 1.f ? c : 1.f);
        float vdiv = (o >= 1) ? gacc[m*68+o]*inv : c;
        sfx[o] = vdiv;
        if (o >= 1) gacc[m*68+o] = vdiv;
    }
    __syncthreads();
    float a = dk[o], v = bv[o];
    for (int i = 0; i < 64; ++i) {
        float xi = sfx[4+i];
        a = fmaf(CkT[i*128+o], xi, a);
        v = fmaf(WvT[i*128+o], xi, v);
    }
    Ak2[m*C+o] = a; xv[m*C+o] = v;
}

// ---------------------------------------------------------------------------
// closed-form BN1 stats from rel moments; fold BN1+pW1 -> w3[4][128].
// reads DIVIDED gacc (proj_m runs first). single block x 256
__global__ __launch_bounds__(256)
void bn1_prep(const float* __restrict__ gacc, const float* __restrict__ posmom,
              const float* __restrict__ pW1, const float* __restrict__ pb1,
              const float* __restrict__ pg1, const float* __restrict__ pbe1,
              float* __restrict__ w3)
{
    __shared__ float sF[8][3], sG[8][6];
    __shared__ float S1[3], S2[6];
    int t = threadIdx.x;
    if (t < 8) {
        float F0=0,F1=0,F2=0,G0=0,G1=0,G2=0,G3=0,G4=0,G5=0;
        for (int k = 0; k < K_; ++k) {
            const float* f = gacc + (t*K_+k)*68 + 1;
            float x=f[0], y=f[1], z=f[2];
            F0+=x; F1+=y; F2+=z;
            G0+=x*x; G1+=x*y; G2+=x*z; G3+=y*y; G4+=y*z; G5+=z*z;
        }
        sF[t][0]=F0; sF[t][1]=F1; sF[t][2]=F2;
        sG[t][0]=G0; sG[t][1]=G1; sG[t][2]=G2; sG[t][3]=G3; sG[t][4]=G4; sG[t][5]=G5;
    }
    __syncthreads();
    if (t == 0) {
        float s1[3]={0,0,0}, s2[6]={0,0,0,0,0,0};
        for (int b = 0; b < 8; ++b) {
            const float* pm = posmom + b*9;
            float Ax=pm[0],Ay=pm[1],Az=pm[2];
            float Fx=sF[b][0],Fy=sF[b][1],Fz=sF[b][2];
            s1[0] += (float)K_*Ax - (float)P_*Fx;
            s1[1] += (float)K_*Ay - (float)P_*Fy;
            s1[2] += (float)K_*Az - (float)P_*Fz;
            s2[0] += (float)K_*pm[3] - 2.f*Ax*Fx + (float)P_*sG[b][0];
            s2[1] += (float)K_*pm[4] - Ax*Fy - Ay*Fx + (float)P_*sG[b][1];
            s2[2] += (float)K_*pm[5] - Ax*Fz - Az*Fx + (float)P_*sG[b][2];
            s2[3] += (float)K_*pm[6] - 2.f*Ay*Fy + (float)P_*sG[b][3];
            s2[4] += (float)K_*pm[7] - Ay*Fz - Az*Fy + (float)P_*sG[b][4];
            s2[5] += (float)K_*pm[8] - 2.f*Az*Fz + (float)P_*sG[b][5];
        }
        for (int i = 0; i < 3; ++i) S1[i] = s1[i];
        for (int i = 0; i < 6; ++i) S2[i] = s2[i];
    }
    __syncthreads();
    if (t < 128) {
        float w0=pW1[t*3], w1=pW1[t*3+1], w2=pW1[t*3+2], bb=pb1[t];
        float wS1 = w0*S1[0] + w1*S1[1] + w2*S1[2];
        float wS2w = w0*w0*S2[0] + w1*w1*S2[3] + w2*w2*S2[5]
                   + 2.f*(w0*w1*S2[1] + w0*w2*S2[2] + w1*w2*S2[4]);
        const float invE = 1.0f/(float)E_;
        float m1  = wS1*invE + bb;
        float Ez2 = (wS2w + 2.f*bb*wS1)*invE + bb*bb;
        float var = Ez2 - m1*m1;
        float sc = pg1[t] * rsqrtf(var + EPS_);
        float sh = pbe1[t] - m1*sc;
        w3[0*128+t] = w0*sc; w3[1*128+t] = w1*sc;
        w3[2*128+t] = w2*sc; w3[3*128+t] = bb*sc + sh;
    }
}

// Aq2[p] = CqT^T@x[p] + dq. 8 points/block. grid 2048 x 256
__global__ __launch_bounds__(256)
void proj_q(const float* __restrict__ x, const float* __restrict__ CqT,
            const float* __restrict__ dq, float* __restrict__ Aq2)
{
    __shared__ float xs[512];
    int tid = threadIdx.x;
    int p0 = blockIdx.x*8;
    const float* xp = x + (size_t)p0*64;
    for (int i = tid; i < 512; i += 256) xs[i] = xp[i];
    __syncthreads();
    int g = tid >> 7, o = tid & 127;
    const float* xb = xs + g*256;
    float d = dq[o];
    float a0=d, a1=d, a2=d, a3=d;
    #pragma unroll 4
    for (int i = 0; i < 64; ++i) {
        float w = CqT[i*128 + o];
        a0 = fmaf(w, xb[i],       a0);
        a1 = fmaf(w, xb[64+i],    a1);
        a2 = fmaf(w, xb[128+i],   a2);
        a3 = fmaf(w, xb[192+i],   a3);
    }
    int pb = p0 + g*4;
    Aq2[(size_t)(pb+0)*C + o] = a0;
    Aq2[(size_t)(pb+1)*C + o] = a1;
    Aq2[(size_t)(pb+2)*C + o] = a2;
    Aq2[(size_t)(pb+3)*C + o] = a3;
}

// ---------------------------------------------------------------------------
// Fused GEMM (R5 structure): 2 tiles/wave, inline BN-affine from raw stat
// replicas (no separate finalize kernel), fused output stats.
// MODE 0: A = BN1-folded pos-MLP layer1 on the fly; +bias; store
// MODE 1: A = relu(zin*sc+sh) [BN from statsin/g/be]; +Aq2[p]-Ak2[m]; store
// MODE 3: A = relu(zin*sc+sh); +bias; NO STORE (stats only)
// grid 2560 x 256
template<int MODE>
__global__ __launch_bounds__(256)
void gemm_fused(const u16* __restrict__ zin, u16* __restrict__ zout,
                const u16* __restrict__ Wbf,
                const float* __restrict__ statsin, const float* __restrict__ g,
                const float* __restrict__ be,
                const float* __restrict__ w3, const float* __restrict__ bias,
                const float* __restrict__ rowq, const float* __restrict__ rowk,
                const float* __restrict__ pos, const float* __restrict__ gacc,
                float* __restrict__ stats32)
{
    __shared__ float s_stat[2][C];
    __shared__ float saff[5*C];

    int tid = threadIdx.x;
    const int wave = tid >> 6, lane = tid & 63;
    const int L = lane & 15, q = lane >> 4;

    ((float*)s_stat)[tid] = 0.f;
    if constexpr (MODE == 0) {
        for (int i = tid; i < 512; i += 256) saff[i] = w3[i];
        if (tid < C) saff[512+tid] = bias[tid];
    } else {
        if (tid < C) {
            float s = 0.f, sq = 0.f;
            for (int r = 0; r < 32; ++r) {
                s  += statsin[r*256 + tid];
                sq += statsin[r*256 + 128 + tid];
            }
            float mean = s*(1.0f/E_), var = sq*(1.0f/E_) - mean*mean;
            float sc = g[tid] * rsqrtf(var + EPS_);
            saff[tid] = sc; saff[C+tid] = be[tid] - mean*sc;
        }
        if constexpr (MODE == 3) {
            if (tid >= 128) saff[2*C + tid - 128] = bias[tid - 128];
        }
    }
    __syncthreads();

    int tbs[2];
    tbs[0] = (blockIdx.x*8 + wave)*16;
    tbs[1] = (blockIdx.x*8 + wave + 4)*16;

    short8 An[2][4];
    float rr0[2], rr1[2], rr2[2];
    #pragma unroll
    for (int tt = 0; tt < 2; ++tt) {
        if constexpr (MODE != 0) {
            const u16* ap = zin + (size_t)(tbs[tt] + L)*C + q*8;
            An[tt][0] = *(const short8*)ap;
            An[tt][1] = *(const short8*)(ap + 32);
            An[tt][2] = *(const short8*)(ap + 64);
            An[tt][3] = *(const short8*)(ap + 96);
        } else {
            unsigned e = (unsigned)(tbs[tt] + L);
            unsigned p = e / 20u; int k = (int)(e - p*20u);
            int m = (int)(p >> 11)*20 + k;
            const float* fp = gacc + m*68 + 1;
            rr0[tt] = pos[p*3]   - fp[0];
            rr1[tt] = pos[p*3+1] - fp[1];
            rr2[tt] = pos[p*3+2] - fp[2];
        }
    }

    floatx4 acc[2][8];
    #pragma unroll
    for (int tt = 0; tt < 2; ++tt)
        #pragma unroll
        for (int ct = 0; ct < 8; ++ct) acc[tt][ct] = (floatx4){0.f,0.f,0.f,0.f};

    #pragma unroll
    for (int ks = 0; ks < 4; ++ks) {
        int ch0 = ks*32 + q*8;
        short8 bfr[8];
        #pragma unroll
        for (int ct = 0; ct < 8; ++ct)
            bfr[ct] = *(const short8*)(Wbf + ((ct*4+ks)*64 + lane)*8);
        #pragma unroll
        for (int tt = 0; tt < 2; ++tt) {
            union { short8 s8; u32 u[4]; } af;
            if constexpr (MODE == 0) {
                #pragma unroll
                for (int jj = 0; jj < 4; ++jj) {
                    int c0 = ch0 + jj*2, c1 = ch0 + jj*2 + 1;
                    float f0 = fmaf(saff[c0], rr0[tt], fmaf(saff[C+c0], rr1[tt],
                               fmaf(saff[2*C+c0], rr2[tt], saff[3*C+c0])));
                    float f1 = fmaf(saff[c1], rr0[tt], fmaf(saff[C+c1], rr1[tt],
                               fmaf(saff[2*C+c1], rr2[tt], saff[3*C+c1])));
                    f0 = f0 > 0.f ? f0 : 0.f;
                    f1 = f1 > 0.f ? f1 : 0.f;
                    af.u[jj] = pkbf(f0, f1);
                }
            } else {
                short8 ar = An[tt][ks];
                #pragma unroll
                for (int jj = 0; jj < 4; ++jj) {
                    int c0 = ch0 + jj*2, c1 = ch0 + jj*2 + 1;
                    float f0 = fmaf(bf2f((u16)ar[jj*2]),   saff[c0], saff[C+c0]);
                    float f1 = fmaf(bf2f((u16)ar[jj*2+1]), saff[c1], saff[C+c1]);
                    f0 = f0 > 0.f ? f0 : 0.f;
                    f1 = f1 > 0.f ? f1 : 0.f;
                    af.u[jj] = pkbf(f0, f1);
                }
            }
            #pragma unroll
            for (int ct = 0; ct < 8; ++ct)
                acc[tt][ct] = __builtin_amdgcn_mfma_f32_16x16x32_bf16(af.s8, bfr[ct], acc[tt][ct], 0, 0, 0);
        }
    }

    float ssum[8], ssq[8];
    #pragma unroll
    for (int i = 0; i < 8; ++i) { ssum[i] = 0.f; ssq[i] = 0.f; }

    #pragma unroll
    for (int tt = 0; tt < 2; ++tt) {
        const int tilebase = tbs[tt];
        int pp[4], mm[4];
        if constexpr (MODE == 1) {
            #pragma unroll
            for (int r = 0; r < 4; ++r) {
                unsigned e2 = (unsigned)(tilebase + q*4 + r);
                unsigned p2 = e2 / 20u; int k2 = (int)(e2 - p2*20u);
                pp[r] = (int)p2; mm[r] = (int)(p2 >> 11)*20 + k2;
            }
        }
        u16* orow = (MODE != 3) ? (zout + (size_t)(tilebase + q*4)*C + L) : nullptr;
        #pragma unroll
        for (int ct = 0; ct < 8; ++ct) {
            int col = ct*16 + L;
            float bb;
            if constexpr (MODE == 0) bb = saff[4*C + col];
            else if constexpr (MODE == 3) bb = saff[2*C + col];
            else bb = 0.f;
            #pragma unroll
            for (int r = 0; r < 4; ++r) {
                float z = acc[tt][ct][r] + bb;
                if constexpr (MODE == 1)
                    z += rowq[pp[r]*C + col] - rowk[mm[r]*C + col];
                ssum[ct] += z; ssq[ct] += z*z;
                if constexpr (MODE != 3)
                    orow[(size_t)r*C + ct*16] = (u16)pkbf(z, z);
            }
        }
    }

    #pragma unroll
    for (int ct = 0; ct < 8; ++ct) {
        float v = ssum[ct]; v += __shfl_xor(v,16); v += __shfl_xor(v,32);
        float w = ssq[ct];  w += __shfl_xor(w,16); w += __shfl_xor(w,32);
        if (lane < 16) {
            atomicAdd(&s_stat[0][ct*16+L], v);
            atomicAdd(&s_stat[1][ct*16+L], w);
        }
    }
    __syncthreads();
    float* dst = stats32 + ((blockIdx.x & 31) << 8);
    atomicAdd(&dst[tid], ((float*)s_stat)[tid]);
}

// ---------------------------------------------------------------------------
// final_fused: recomputes za2 tiles from za1 (gemm3 K-loop), applies BN4 +
// exp, delta = relu(BN2(z2)), accumulates per-point num/den in registers.
// Each wave: 80 rows = 4 points = 5 tiles (point boundaries compile-time).
// Inline BN2/BN3/BN4 from raw stat replicas. grid 1024 x 256
__global__ __launch_bounds__(256)
void final_fused(const u16* __restrict__ z2, const u16* __restrict__ za1,
                 const u16* __restrict__ Wbf,
                 const float* __restrict__ stA, const float* __restrict__ pg2,
                 const float* __restrict__ pbe2,
                 const float* __restrict__ stB, const float* __restrict__ ag1,
                 const float* __restrict__ abe1,
                 const float* __restrict__ stC, const float* __restrict__ ag2,
                 const float* __restrict__ abe2,
                 const float* __restrict__ ab2, const float* __restrict__ xv,
                 float* __restrict__ out)
{
    __shared__ float saff[7*C];   // sc3,sh3,sc4,sh4,sc2,sh2,ab2
    __shared__ float sxv[20*132];
    int tid = threadIdx.x;
    if (tid < C) {
        float s=0.f, sq=0.f;
        for (int r = 0; r < 32; ++r) { s += stB[r*256+tid]; sq += stB[r*256+128+tid]; }
        float mean = s*(1.0f/E_), var = sq*(1.0f/E_)-mean*mean;
        float sc = ag1[tid]*rsqrtf(var+EPS_);
        saff[tid] = sc; saff[C+tid] = abe1[tid]-mean*sc;
        s=0.f; sq=0.f;
        for (int r = 0; r < 32; ++r) { s += stA[r*256+tid]; sq += stA[r*256+128+tid]; }
        mean = s*(1.0f/E_); var = sq*(1.0f/E_)-mean*mean;
        sc = pg2[tid]*rsqrtf(var+EPS_);
        saff[4*C+tid] = sc; saff[5*C+tid] = pbe2[tid]-mean*sc;
    } else {
        int c = tid - C;
        float s=0.f, sq=0.f;
        for (int r = 0; r < 32; ++r) { s += stC[r*256+c]; sq += stC[r*256+128+c]; }
        float mean = s*(1.0f/E_), var = sq*(1.0f/E_)-mean*mean;
        float sc = ag2[c]*rsqrtf(var+EPS_);
        saff[2*C+c] = sc; saff[3*C+c] = abe2[c]-mean*sc;
        saff[6*C+c] = ab2[c];
    }
    int w = tid >> 6, lane = tid & 63;
    int p0blk = blockIdx.x * 16;
    int graph = p0blk >> 11;
    const float* xvg = xv + (size_t)graph*20*C;
    for (int i = tid; i < 20*C; i += 256) sxv[(i>>7)*132 + (i&127)] = xvg[i];
    __syncthreads();

    const int L = lane & 15, q = lane >> 4;
    const int wavebase = blockIdx.x*320 + w*80;
    const int p0 = p0blk + w*4;

    float num[4][8], den[4][8];
    #pragma unroll
    for (int a = 0; a < 4; ++a)
        #pragma unroll
        for (int c = 0; c < 8; ++c) { num[a][c] = 0.f; den[a][c] = 0.f; }

    const int lpA_t[5]    = {0, 0, 1, 2, 3};
    const int rsplit_t[5] = {16, 4, 8, 12, 16};

    #pragma unroll
    for (int t = 0; t < 5; ++t) {
        const int tilebase = wavebase + t*16;
        const u16* ap = za1 + (size_t)(tilebase + L)*C + q*8;
        short8 Ar[4];
        Ar[0] = *(const short8*)ap;
        Ar[1] = *(const short8*)(ap + 32);
        Ar[2] = *(const short8*)(ap + 64);
        Ar[3] = *(const short8*)(ap + 96);

        floatx4 acc[8];
        #pragma unroll
        for (int ct = 0; ct < 8; ++ct) acc[ct] = (floatx4){0.f,0.f,0.f,0.f};

        #pragma unroll
        for (int ks = 0; ks < 4; ++ks) {
            int ch0 = ks*32 + q*8;
            short8 ar = Ar[ks];
            union { short8 s8; u32 u[4]; } af;
            #pragma unroll
            for (int jj = 0; jj < 4; ++jj) {
                int c0 = ch0 + jj*2, c1 = ch0 + jj*2 + 1;
                float f0 = fmaf(bf2f((u16)ar[jj*2]),   saff[c0], saff[C+c0]);
                float f1 = fmaf(bf2f((u16)ar[jj*2+1]), saff[c1], saff[C+c1]);
                f0 = f0 > 0.f ? f0 : 0.f;
                f1 = f1 > 0.f ? f1 : 0.f;
                af.u[jj] = pkbf(f0, f1);
            }
            #pragma unroll
            for (int ct = 0; ct < 8; ++ct) {
                short8 bfr = *(const short8*)(Wbf + ((ct*4+ks)*64 + lane)*8);
                acc[ct] = __builtin_amdgcn_mfma_f32_16x16x32_bf16(af.s8, bfr, acc[ct], 0, 0, 0);
            }
        }

        const int lpA = lpA_t[t], rs = rsplit_t[t];
        #pragma unroll
        for (int ct = 0; ct < 8; ++ct) {
            int col = ct*16 + L;
            float sc4v = saff[2*C+col], sh4v = saff[3*C+col];
            float sc2v = saff[4*C+col], sh2v = saff[5*C+col];
            float bb   = saff[6*C+col];
            float eA = 0.f, evA = 0.f, eB = 0.f, evB = 0.f;
            #pragma unroll
            for (int r = 0; r < 4; ++r) {
                int rloc = q*4 + r;
                int row = tilebase + rloc;
                float za2v = acc[ct][r] + bb;
                float a = fmaf(sc4v, za2v, sh4v); a = a > 0.f ? a : 0.f;
                float e_ = __expf(a);
                float zz = bf2f(z2[(size_t)row*C + col]);
                float dd = fmaf(sc2v, zz, sh2v); dd = dd > 0.f ? dd : 0.f;
                bool isB = rloc >= rs;
                int lp = isB ? lpA + 1 : lpA;
                int k  = t*16 + rloc - 20*lp;
                float v = sxv[k*132 + col] + dd;
                if (isB) { eB += e_; evB += e_*v; }
                else     { eA += e_; evA += e_*v; }
            }
            num[lpA][ct] += evA; den[lpA][ct] += eA;
            if (rs < 16) { num[lpA+1][ct] += evB; den[lpA+1][ct] += eB; }
        }
    }

    // reduce over the 4 q-groups
    #pragma unroll
    for (int a = 0; a < 4; ++a)
        #pragma unroll
        for (int c = 0; c < 8; ++c) {
            float n = num[a][c], d = den[a][c];
            n += __shfl_xor(n, 16); n += __shfl_xor(n, 32);
            d += __shfl_xor(d, 16); d += __shfl_xor(d, 32);
            num[a][c] = n; den[a][c] = d;
        }
    // lane (L,q) stores point q, channels ct*16+L
    float* op = out + (size_t)(p0 + q)*C + L;
    #pragma unroll
    for (int c = 0; c < 8; ++c)
        op[c*16] = num[q][c] / den[q][c];
}

// ---------------------------------------------------------------------------
extern "C" void kernel_launch(void* const* d_in, const int* in_sizes, int n_in,
                              void* d_out, int out_size, void* d_ws, size_t ws_size,
                              hipStream_t stream)
{
    const float* x    = (const float*)d_in[0];
    const float* pos  = (const float*)d_in[1];
    const float* Wq   = (const float*)d_in[2];
    const float* bq   = (const float*)d_in[3];
    const float* Wk   = (const float*)d_in[4];
    const float* bk   = (const float*)d_in[5];
    const float* Wv   = (const float*)d_in[6];
    const float* bv   = (const float*)d_in[7];
    const float* pW1  = (const float*)d_in[8];
    const float* pb1  = (const float*)d_in[9];
    const float* pg1  = (const float*)d_in[10];
    const float* pbe1 = (const float*)d_in[11];
    const float* pW2  = (const float*)d_in[12];
    const float* pb2  = (const float*)d_in[13];
    const float* pg2  = (const float*)d_in[14];
    const float* pbe2 = (const float*)d_in[15];
    const float* aW1  = (const float*)d_in[16];
    const float* ab1  = (const float*)d_in[17];
    const float* ag1  = (const float*)d_in[18];
    const float* abe1 = (const float*)d_in[19];
    const float* aW2  = (const float*)d_in[20];
    const float* ab2  = (const float*)d_in[21];
    const float* ag2  = (const float*)d_in[22];
    const float* abe2 = (const float*)d_in[23];
    const int* fps_idx = (const int*)d_in[24];
    float* out = (float*)d_out;

    char* ws = (char*)d_ws;
    size_t off = 0;
    auto alloc = [&](size_t bytes) -> void* {
        void* r = ws + off;
        off = (off + bytes + 255) & ~(size_t)255;
        return r;
    };
    float* gacc    = (float*)alloc(160*68*4);        // zeroed
    float* posmom  = (float*)alloc(8*9*4);           // zeroed
    float* stats32 = (float*)alloc(3*32*256*4);      // zeroed
    size_t zero_bytes = off;
    float* w3  = (float*)alloc(4*128*4);
    float* CqT = (float*)alloc(64*128*4);
    float* CkT = (float*)alloc(64*128*4);
    float* dq  = (float*)alloc(128*4);
    float* dk  = (float*)alloc(128*4);
    float* WvT = (float*)alloc(64*128*4);
    u16* Wb0   = (u16*)alloc(128*128*2);
    u16* Wb1   = (u16*)alloc(128*128*2);
    u16* Wb2   = (u16*)alloc(128*128*2);
    float* Aq2 = (float*)alloc((size_t)N_*128*4);
    float* Ak2 = (float*)alloc(160*128*4);
    float* xv  = (float*)alloc(160*128*4);
    u16* bigA  = (u16*)alloc((size_t)E_*128*2);      // z2
    u16* bigB  = (u16*)alloc((size_t)E_*128*2);      // za1

    hipMemsetAsync(d_ws, 0, zero_bytes, stream);

    prep_weights<<<69, 256, 0, stream>>>(Wq, bq, Wk, bk, aW1, ab1, pW2, aW2, Wv,
                                         CqT, CkT, dq, dk, WvT, Wb0, Wb1, Wb2);
    knn_scatter<<<256, 256, 0, stream>>>(pos, x, fps_idx, gacc, posmom);
    proj_m<<<160, 128, 0, stream>>>(gacc, CkT, dk, WvT, bv, Ak2, xv);
    bn1_prep<<<1, 256, 0, stream>>>(gacc, posmom, pW1, pb1, pg1, pbe1, w3);
    proj_q<<<N_/8, 256, 0, stream>>>(x, CqT, dq, Aq2);

    float* stA = stats32;
    float* stB = stats32 + 32*256;
    float* stC = stats32 + 2*32*256;

    // gemm1: rel -> z2 (bias pb2), stats of z2 -> stA
    gemm_fused<0><<<E_/128, 256, 0, stream>>>(nullptr, bigA, Wb0,
        nullptr, nullptr, nullptr, w3, pb2, nullptr, nullptr, pos, gacc, stA);

    // gemm2: z2 -> za1 (+Aq2-Ak2), BN2 inline from stA, stats -> stB
    gemm_fused<1><<<E_/128, 256, 0, stream>>>(bigA, bigB, Wb1,
        stA, pg2, pbe2, nullptr, nullptr, Aq2, Ak2, nullptr, nullptr, stB);

    // gemm3s: za1 stats-only pass, BN3 inline from stB, bias ab2, stats -> stC
    gemm_fused<3><<<E_/128, 256, 0, stream>>>(bigB, nullptr, Wb2,
        stB, ag1, abe1, nullptr, ab2, nullptr, nullptr, nullptr, nullptr, stC);

    // final: recompute za2 from za1, softmax, out
    final_fused<<<N_/16, 256, 0, stream>>>(bigA, bigB, Wb2,
        stA, pg2, pbe2, stB, ag1, abe1, stC, ag2, abe2, ab2, xv, out);
}

// Round 9
// 365.932 us; speedup vs baseline: 1.3421x; 1.3421x over previous
//
#include <hip/hip_runtime.h>
#include <hip/hip_bf16.h>
#include <stdint.h>

#define B_ 8
#define P_ 2048
#define K_ 20
#define N_ (B_*P_)     // 16384
#define M_ (B_*K_)     // 160
#define C 128
#define E_ (N_*K_)     // 327680
#define EPS_ 1e-5f

typedef unsigned short u16;
typedef unsigned int u32;
typedef __attribute__((ext_vector_type(8))) short short8;
typedef __attribute__((ext_vector_type(4))) float floatx4;

__device__ __forceinline__ float bf2f(u16 u){
    union { u32 i; float f; } v; v.i = ((u32)u) << 16; return v.f;
}
__device__ __forceinline__ u16 f2bf(float f){
    union { float f; u32 i; } v; v.f = f;
    u32 r = ((v.i >> 16) & 1u) + 0x7fffu;
    return (u16)((v.i + r) >> 16);
}
__device__ __forceinline__ u32 pkbf(float a, float b){
    union { __hip_bfloat162 h; u32 u; } cv;
    cv.h = __float22bfloat162_rn(make_float2(a, b));
    return cv.u;
}

// ---------------------------------------------------------------------------
// prep: CqT = (aW1@Wq)^T [64,128], CkT = (aW1@Wk)^T, dq = aW1@bq + ab1,
//       dk = aW1@bk, WvT [64,128], frag-major bf16 copies of pW2, aW1, aW2.
// grid 69 x 256
__global__ __launch_bounds__(256)
void prep_weights(const float* __restrict__ Wq, const float* __restrict__ bq,
                  const float* __restrict__ Wk, const float* __restrict__ bk,
                  const float* __restrict__ aW1, const float* __restrict__ ab1,
                  const float* __restrict__ pW2, const float* __restrict__ aW2,
                  const float* __restrict__ Wv,
                  float* __restrict__ CqT, float* __restrict__ CkT,
                  float* __restrict__ dq, float* __restrict__ dk,
                  float* __restrict__ WvT,
                  u16* __restrict__ Wb0, u16* __restrict__ Wb1, u16* __restrict__ Wb2)
{
    int tid = threadIdx.x, blk = blockIdx.x;
    if (blk < 32) {
        int idx = blk*256 + tid; int o = idx >> 6, i = idx & 63;
        float s = 0.f;
        for (int cc = 0; cc < 128; ++cc) s = fmaf(aW1[o*128+cc], Wq[cc*64+i], s);
        CqT[i*128 + o] = s;
    } else if (blk < 64) {
        int idx = (blk-32)*256 + tid; int o = idx >> 6, i = idx & 63;
        float s = 0.f;
        for (int cc = 0; cc < 128; ++cc) s = fmaf(aW1[o*128+cc], Wk[cc*64+i], s);
        CkT[i*128 + o] = s;
    } else if (blk == 64) {
        if (tid < 128) {
            float s = ab1[tid];
            for (int cc = 0; cc < 128; ++cc) s = fmaf(aW1[tid*128+cc], bq[cc], s);
            dq[tid] = s;
        } else {
            int o = tid - 128;
            float s = 0.f;
            for (int cc = 0; cc < 128; ++cc) s = fmaf(aW1[o*128+cc], bk[cc], s);
            dk[o] = s;
        }
    } else if (blk == 68) {
        for (int idx = tid; idx < 8192; idx += 256) {
            int o = idx >> 6, i = idx & 63;
            WvT[i*128 + o] = Wv[idx];
        }
    } else {
        // frag-major remap: slot s = (ct*4+ks)*64 + lane, 8 u16 per slot.
        const float* src = (blk == 65) ? pW2 : (blk == 66) ? aW1 : aW2;
        u16* dst = (blk == 65) ? Wb0 : (blk == 66) ? Wb1 : Wb2;
        for (int s = tid; s < 2048; s += 256) {
            int ln = s & 63, ks = (s >> 6) & 3, ct = s >> 8;
            int Ls = ln & 15, qs = ln >> 4;
            const float* sp = src + (ct*16+Ls)*C + ks*32 + qs*8;
            #pragma unroll
            for (int j = 0; j < 8; ++j) dst[s*8+j] = f2bf(sp[j]);
        }
    }
}

// ---------------------------------------------------------------------------
// knn + kernel-weighted scatter into gacc[m][68] + per-graph pos moments.
// grid 256 x 256
__global__ __launch_bounds__(256)
void knn_scatter(const float* __restrict__ pos, const float* __restrict__ x,
                 const int* __restrict__ fps_idx, float* __restrict__ gacc,
                 float* __restrict__ posmom)
{
    __shared__ float fpos[K_][3];
    __shared__ float accL[K_*68];
    __shared__ int   skb[64];
    __shared__ float sek[64];
    int tid = threadIdx.x;
    int b = blockIdx.x >> 5;              // 32 blocks per graph
    if (tid < K_*3) {
        int k = tid / 3, d = tid - k*3;
        fpos[k][d] = pos[fps_idx[b*K_+k]*3 + d];
    }
    for (int i = tid; i < K_*68; i += 256) accL[i] = 0.f;
    __syncthreads();

    int wbase = blockIdx.x*64;
    if (tid < 64) {
        int p = wbase + tid;
        float px = pos[p*3], py = pos[p*3+1], pz = pos[p*3+2];
        float best = 1e30f; int kb = 0;
        #pragma unroll
        for (int k = 0; k < K_; ++k) {
            float dx = px - fpos[k][0], dy = py - fpos[k][1], dz = pz - fpos[k][2];
            float d2 = dx*dx + dy*dy + dz*dz;
            if (d2 < best) { best = d2; kb = k; }   // strict <: argmin keeps first
        }
        float ek = 1.0f / (1.0f + 5.0f*best);
        skb[tid] = kb; sek[tid] = ek;
        atomicAdd(&accL[kb*68 + 0], 1.0f);
        atomicAdd(&accL[kb*68 + 1], ek*px);
        atomicAdd(&accL[kb*68 + 2], ek*py);
        atomicAdd(&accL[kb*68 + 3], ek*pz);

        float mom[9] = {px,py,pz, px*px,px*py,px*pz, py*py,py*pz, pz*pz};
        #pragma unroll
        for (int i = 0; i < 9; ++i) {
            float v = mom[i];
            v += __shfl_xor(v,32); v += __shfl_xor(v,16); v += __shfl_xor(v,8);
            v += __shfl_xor(v,4);  v += __shfl_xor(v,2);  v += __shfl_xor(v,1);
            mom[i] = v;
        }
        if (tid == 0) {
            #pragma unroll
            for (int i = 0; i < 9; ++i) atomicAdd(&posmom[b*9+i], mom[i]);
        }
    }
    __syncthreads();

    int w = tid >> 6, lane = tid & 63;
    #pragma unroll
    for (int jj = 0; jj < 16; ++jj) {
        int j = w*16 + jj;
        int   kbj = skb[j];
        float ekj = sek[j];
        float xvv = x[(size_t)(wbase+j)*64 + lane];
        atomicAdd(&accL[kbj*68 + 4 + lane], ekj*xvv);
    }
    __syncthreads();
    for (int i = tid; i < K_*68; i += 256)
        atomicAdd(&gacc[b*K_*68 + i], accL[i]);
}

// ---------------------------------------------------------------------------
// proj_m + fps divide: divides gacc row m in place (for bn1_prep & gemm1),
// then Ak2[m] = Ck@fps_x + dk ; xv[m] = Wv@fps_x + bv. grid 160 x 128
__global__ __launch_bounds__(128)
void proj_m(float* __restrict__ gacc, const float* __restrict__ CkT,
            const float* __restrict__ dk, const float* __restrict__ WvT,
            const float* __restrict__ bv, float* __restrict__ Ak2,
            float* __restrict__ xv)
{
    __shared__ float sfx[68];
    int m = blockIdx.x, o = threadIdx.x;
    if (o < 68) {
        float c = gacc[m*68];
        float inv = 1.0f / (c > 1.f ? c : 1.f);
        float vdiv = (o >= 1) ? gacc[m*68+o]*inv : c;
        sfx[o] = vdiv;
        if (o >= 1) gacc[m*68+o] = vdiv;
    }
    __syncthreads();
    float a = dk[o], v = bv[o];
    for (int i = 0; i < 64; ++i) {
        float xi = sfx[4+i];
        a = fmaf(CkT[i*128+o], xi, a);
        v = fmaf(WvT[i*128+o], xi, v);
    }
    Ak2[m*C+o] = a; xv[m*C+o] = v;
}

// ---------------------------------------------------------------------------
// closed-form BN1 stats from rel moments; fold BN1+pW1 -> w3[4][128].
// reads DIVIDED gacc (proj_m runs first). single block x 256
__global__ __launch_bounds__(256)
void bn1_prep(const float* __restrict__ gacc, const float* __restrict__ posmom,
              const float* __restrict__ pW1, const float* __restrict__ pb1,
              const float* __restrict__ pg1, const float* __restrict__ pbe1,
              float* __restrict__ w3)
{
    __shared__ float sF[8][3], sG[8][6];
    __shared__ float S1[3], S2[6];
    int t = threadIdx.x;
    if (t < 8) {
        float F0=0,F1=0,F2=0,G0=0,G1=0,G2=0,G3=0,G4=0,G5=0;
        for (int k = 0; k < K_; ++k) {
            const float* f = gacc + (t*K_+k)*68 + 1;
            float x=f[0], y=f[1], z=f[2];
            F0+=x; F1+=y; F2+=z;
            G0+=x*x; G1+=x*y; G2+=x*z; G3+=y*y; G4+=y*z; G5+=z*z;
        }
        sF[t][0]=F0; sF[t][1]=F1; sF[t][2]=F2;
        sG[t][0]=G0; sG[t][1]=G1; sG[t][2]=G2; sG[t][3]=G3; sG[t][4]=G4; sG[t][5]=G5;
    }
    __syncthreads();
    if (t == 0) {
        float s1[3]={0,0,0}, s2[6]={0,0,0,0,0,0};
        for (int b = 0; b < 8; ++b) {
            const float* pm = posmom + b*9;
            float Ax=pm[0],Ay=pm[1],Az=pm[2];
            float Fx=sF[b][0],Fy=sF[b][1],Fz=sF[b][2];
            s1[0] += (float)K_*Ax - (float)P_*Fx;
            s1[1] += (float)K_*Ay - (float)P_*Fy;
            s1[2] += (float)K_*Az - (float)P_*Fz;
            s2[0] += (float)K_*pm[3] - 2.f*Ax*Fx + (float)P_*sG[b][0];
            s2[1] += (float)K_*pm[4] - Ax*Fy - Ay*Fx + (float)P_*sG[b][1];
            s2[2] += (float)K_*pm[5] - Ax*Fz - Az*Fx + (float)P_*sG[b][2];
            s2[3] += (float)K_*pm[6] - 2.f*Ay*Fy + (float)P_*sG[b][3];
            s2[4] += (float)K_*pm[7] - Ay*Fz - Az*Fy + (float)P_*sG[b][4];
            s2[5] += (float)K_*pm[8] - 2.f*Az*Fz + (float)P_*sG[b][5];
        }
        for (int i = 0; i < 3; ++i) S1[i] = s1[i];
        for (int i = 0; i < 6; ++i) S2[i] = s2[i];
    }
    __syncthreads();
    if (t < 128) {
        float w0=pW1[t*3], w1=pW1[t*3+1], w2=pW1[t*3+2], bb=pb1[t];
        float wS1 = w0*S1[0] + w1*S1[1] + w2*S1[2];
        float wS2w = w0*w0*S2[0] + w1*w1*S2[3] + w2*w2*S2[5]
                   + 2.f*(w0*w1*S2[1] + w0*w2*S2[2] + w1*w2*S2[4]);
        const float invE = 1.0f/(float)E_;
        float m1  = wS1*invE + bb;
        float Ez2 = (wS2w + 2.f*bb*wS1)*invE + bb*bb;
        float var = Ez2 - m1*m1;
        float sc = pg1[t] * rsqrtf(var + EPS_);
        float sh = pbe1[t] - m1*sc;
        w3[0*128+t] = w0*sc; w3[1*128+t] = w1*sc;
        w3[2*128+t] = w2*sc; w3[3*128+t] = bb*sc + sh;
    }
}

// Aq2[p] = CqT^T@x[p] + dq. 8 points/block. grid 2048 x 256
__global__ __launch_bounds__(256)
void proj_q(const float* __restrict__ x, const float* __restrict__ CqT,
            const float* __restrict__ dq, float* __restrict__ Aq2)
{
    __shared__ float xs[512];
    int tid = threadIdx.x;
    int p0 = blockIdx.x*8;
    const float* xp = x + (size_t)p0*64;
    for (int i = tid; i < 512; i += 256) xs[i] = xp[i];
    __syncthreads();
    int g = tid >> 7, o = tid & 127;
    const float* xb = xs + g*256;
    float d = dq[o];
    float a0=d, a1=d, a2=d, a3=d;
    #pragma unroll 4
    for (int i = 0; i < 64; ++i) {
        float w = CqT[i*128 + o];
        a0 = fmaf(w, xb[i],       a0);
        a1 = fmaf(w, xb[64+i],    a1);
        a2 = fmaf(w, xb[128+i],   a2);
        a3 = fmaf(w, xb[192+i],   a3);
    }
    int pb = p0 + g*4;
    Aq2[(size_t)(pb+0)*C + o] = a0;
    Aq2[(size_t)(pb+1)*C + o] = a1;
    Aq2[(size_t)(pb+2)*C + o] = a2;
    Aq2[(size_t)(pb+3)*C + o] = a3;
}

// ---------------------------------------------------------------------------
// Fused GEMM (R5 structure + inline BN prologue + NONTEMPORAL stores):
// 2 tiles/wave, no hot-loop barriers, fused output stats into 32-way
// replicated global accumulators.
// MODE 0: A = BN1-folded pos-MLP layer1 on the fly; +bias(pb2); store z2
// MODE 1: A = relu(zin*sc+sh) [BN from statsin]; +Aq2[p]-Ak2[m]; store za1
// MODE 2: A = relu(zin*sc+sh) [BN from statsin]; +bias(ab2); store za2
// grid 2560 x 256
template<int MODE>
__global__ __launch_bounds__(256)
void gemm_fused(const u16* __restrict__ zin, u16* __restrict__ zout,
                const u16* __restrict__ Wbf,
                const float* __restrict__ statsin, const float* __restrict__ g,
                const float* __restrict__ be,
                const float* __restrict__ w3, const float* __restrict__ bias,
                const float* __restrict__ rowq, const float* __restrict__ rowk,
                const float* __restrict__ pos, const float* __restrict__ gacc,
                float* __restrict__ stats32)
{
    __shared__ float s_stat[2][C];
    __shared__ float saff[5*C];

    int tid = threadIdx.x;
    const int wave = tid >> 6, lane = tid & 63;
    const int L = lane & 15, q = lane >> 4;

    ((float*)s_stat)[tid] = 0.f;
    if constexpr (MODE == 0) {
        for (int i = tid; i < 512; i += 256) saff[i] = w3[i];
        if (tid < C) saff[512+tid] = bias[tid];
    } else {
        if (tid < C) {
            float s = 0.f, sq = 0.f;
            for (int r = 0; r < 32; ++r) {
                s  += statsin[r*256 + tid];
                sq += statsin[r*256 + 128 + tid];
            }
            float mean = s*(1.0f/E_), var = sq*(1.0f/E_) - mean*mean;
            float sc = g[tid] * rsqrtf(var + EPS_);
            saff[tid] = sc; saff[C+tid] = be[tid] - mean*sc;
        }
        if constexpr (MODE == 2) {
            if (tid >= 128) saff[2*C + tid - 128] = bias[tid - 128];
        }
    }
    __syncthreads();

    int tbs[2];
    tbs[0] = (blockIdx.x*8 + wave)*16;
    tbs[1] = (blockIdx.x*8 + wave + 4)*16;

    short8 An[2][4];
    float rr0[2], rr1[2], rr2[2];
    #pragma unroll
    for (int tt = 0; tt < 2; ++tt) {
        if constexpr (MODE != 0) {
            const u16* ap = zin + (size_t)(tbs[tt] + L)*C + q*8;
            An[tt][0] = *(const short8*)ap;
            An[tt][1] = *(const short8*)(ap + 32);
            An[tt][2] = *(const short8*)(ap + 64);
            An[tt][3] = *(const short8*)(ap + 96);
        } else {
            unsigned e = (unsigned)(tbs[tt] + L);
            unsigned p = e / 20u; int k = (int)(e - p*20u);
            int m = (int)(p >> 11)*20 + k;
            const float* fp = gacc + m*68 + 1;
            rr0[tt] = pos[p*3]   - fp[0];
            rr1[tt] = pos[p*3+1] - fp[1];
            rr2[tt] = pos[p*3+2] - fp[2];
        }
    }

    floatx4 acc[2][8];
    #pragma unroll
    for (int tt = 0; tt < 2; ++tt)
        #pragma unroll
        for (int ct = 0; ct < 8; ++ct) acc[tt][ct] = (floatx4){0.f,0.f,0.f,0.f};

    #pragma unroll
    for (int ks = 0; ks < 4; ++ks) {
        int ch0 = ks*32 + q*8;
        short8 bfr[8];
        #pragma unroll
        for (int ct = 0; ct < 8; ++ct)
            bfr[ct] = *(const short8*)(Wbf + ((ct*4+ks)*64 + lane)*8);
        #pragma unroll
        for (int tt = 0; tt < 2; ++tt) {
            union { short8 s8; u32 u[4]; } af;
            if constexpr (MODE == 0) {
                #pragma unroll
                for (int jj = 0; jj < 4; ++jj) {
                    int c0 = ch0 + jj*2, c1 = ch0 + jj*2 + 1;
                    float f0 = fmaf(saff[c0], rr0[tt], fmaf(saff[C+c0], rr1[tt],
                               fmaf(saff[2*C+c0], rr2[tt], saff[3*C+c0])));
                    float f1 = fmaf(saff[c1], rr0[tt], fmaf(saff[C+c1], rr1[tt],
                               fmaf(saff[2*C+c1], rr2[tt], saff[3*C+c1])));
                    f0 = f0 > 0.f ? f0 : 0.f;
                    f1 = f1 > 0.f ? f1 : 0.f;
                    af.u[jj] = pkbf(f0, f1);
                }
            } else {
                short8 ar = An[tt][ks];
                #pragma unroll
                for (int jj = 0; jj < 4; ++jj) {
                    int c0 = ch0 + jj*2, c1 = ch0 + jj*2 + 1;
                    float f0 = fmaf(bf2f((u16)ar[jj*2]),   saff[c0], saff[C+c0]);
                    float f1 = fmaf(bf2f((u16)ar[jj*2+1]), saff[c1], saff[C+c1]);
                    f0 = f0 > 0.f ? f0 : 0.f;
                    f1 = f1 > 0.f ? f1 : 0.f;
                    af.u[jj] = pkbf(f0, f1);
                }
            }
            #pragma unroll
            for (int ct = 0; ct < 8; ++ct)
                acc[tt][ct] = __builtin_amdgcn_mfma_f32_16x16x32_bf16(af.s8, bfr[ct], acc[tt][ct], 0, 0, 0);
        }
    }

    float ssum[8], ssq[8];
    #pragma unroll
    for (int i = 0; i < 8; ++i) { ssum[i] = 0.f; ssq[i] = 0.f; }

    #pragma unroll
    for (int tt = 0; tt < 2; ++tt) {
        const int tilebase = tbs[tt];
        int pp[4], mm[4];
        if constexpr (MODE == 1) {
            #pragma unroll
            for (int r = 0; r < 4; ++r) {
                unsigned e2 = (unsigned)(tilebase + q*4 + r);
                unsigned p2 = e2 / 20u; int k2 = (int)(e2 - p2*20u);
                pp[r] = (int)p2; mm[r] = (int)(p2 >> 11)*20 + k2;
            }
        }
        u16* orow = zout + (size_t)(tilebase + q*4)*C + L;
        #pragma unroll
        for (int ct = 0; ct < 8; ++ct) {
            int col = ct*16 + L;
            float bb;
            if constexpr (MODE == 0) bb = saff[4*C + col];
            else if constexpr (MODE == 2) bb = saff[2*C + col];
            else bb = 0.f;
            #pragma unroll
            for (int r = 0; r < 4; ++r) {
                float z = acc[tt][ct][r] + bb;
                if constexpr (MODE == 1)
                    z += rowq[pp[r]*C + col] - rowk[mm[r]*C + col];
                ssum[ct] += z; ssq[ct] += z*z;
                __builtin_nontemporal_store((u16)pkbf(z, z),
                                            &orow[(size_t)r*C + ct*16]);
            }
        }
    }

    #pragma unroll
    for (int ct = 0; ct < 8; ++ct) {
        float v = ssum[ct]; v += __shfl_xor(v,16); v += __shfl_xor(v,32);
        float w = ssq[ct];  w += __shfl_xor(w,16); w += __shfl_xor(w,32);
        if (lane < 16) {
            atomicAdd(&s_stat[0][ct*16+L], v);
            atomicAdd(&s_stat[1][ct*16+L], w);
        }
    }
    __syncthreads();
    float* dst = stats32 + ((blockIdx.x & 31) << 8);
    atomicAdd(&dst[tid], ((float*)s_stat)[tid]);
}

// ---------------------------------------------------------------------------
// final: alpha = softmax_k(relu(BN4(za2))); delta = relu(BN2(z2));
// out[p,c] = sum_k alpha*(xv[m,c]+delta). BN2/BN4 affines reduced inline
// from raw stat replicas. 2 channels/lane, 4 points/block. grid 4096 x 256
__global__ __launch_bounds__(256)
void final_kernel(const u16* __restrict__ z2, const u16* __restrict__ za2,
                  const float* __restrict__ stA, const float* __restrict__ pg2,
                  const float* __restrict__ pbe2,
                  const float* __restrict__ stC, const float* __restrict__ ag2,
                  const float* __restrict__ abe2,
                  const float* __restrict__ xv, float* __restrict__ out)
{
    __shared__ float saff[4*C];   // sc2, sh2, sc4, sh4
    int tid = threadIdx.x;
    if (tid < C) {
        float s=0.f, sq=0.f;
        for (int r = 0; r < 32; ++r) { s += stA[r*256+tid]; sq += stA[r*256+128+tid]; }
        float mean = s*(1.0f/E_), var = sq*(1.0f/E_)-mean*mean;
        float sc = pg2[tid]*rsqrtf(var+EPS_);
        saff[tid] = sc; saff[C+tid] = pbe2[tid]-mean*sc;
    } else {
        int c = tid - C;
        float s=0.f, sq=0.f;
        for (int r = 0; r < 32; ++r) { s += stC[r*256+c]; sq += stC[r*256+128+c]; }
        float mean = s*(1.0f/E_), var = sq*(1.0f/E_)-mean*mean;
        float sc = ag2[c]*rsqrtf(var+EPS_);
        saff[2*C+c] = sc; saff[3*C+c] = abe2[c]-mean*sc;
    }
    __syncthreads();

    int p = blockIdx.x*4 + (tid >> 6);
    int lane = tid & 63;
    int c2 = lane*2;
    int b = p >> 11;
    float S2x=saff[c2], S2y=saff[c2+1], H2x=saff[C+c2], H2y=saff[C+c2+1];
    float S4x=saff[2*C+c2], S4y=saff[2*C+c2+1], H4x=saff[3*C+c2], H4y=saff[3*C+c2+1];
    size_t ebase = (size_t)p * K_;
    const float* xvb = xv + (size_t)(b*K_)*C + c2;
    float l0 = 0.f, l1 = 0.f, o0 = 0.f, o1 = 0.f;
    #pragma unroll
    for (int k = 0; k < K_; ++k) {
        u32 wa = *(const u32*)(za2 + (ebase+k)*C + c2);
        u32 wz = *(const u32*)(z2  + (ebase+k)*C + c2);
        float2 xvv = *(const float2*)(xvb + (size_t)k*C);
        float aa0 = fmaf(bf2f((u16)(wa & 0xffffu)), S4x, H4x); aa0 = aa0 > 0.f ? aa0 : 0.f;
        float aa1 = fmaf(bf2f((u16)(wa >> 16)),     S4y, H4y); aa1 = aa1 > 0.f ? aa1 : 0.f;
        float dd0 = fmaf(bf2f((u16)(wz & 0xffffu)), S2x, H2x); dd0 = dd0 > 0.f ? dd0 : 0.f;
        float dd1 = fmaf(bf2f((u16)(wz >> 16)),     S2y, H2y); dd1 = dd1 > 0.f ? dd1 : 0.f;
        float e0 = __expf(aa0), e1 = __expf(aa1);
        l0 += e0; l1 += e1;
        o0 = fmaf(e0, xvv.x + dd0, o0);
        o1 = fmaf(e1, xvv.y + dd1, o1);
    }
    out[(size_t)p*C + c2]     = o0 / l0;
    out[(size_t)p*C + c2 + 1] = o1 / l1;
}

// ---------------------------------------------------------------------------
extern "C" void kernel_launch(void* const* d_in, const int* in_sizes, int n_in,
                              void* d_out, int out_size, void* d_ws, size_t ws_size,
                              hipStream_t stream)
{
    const float* x    = (const float*)d_in[0];
    const float* pos  = (const float*)d_in[1];
    const float* Wq   = (const float*)d_in[2];
    const float* bq   = (const float*)d_in[3];
    const float* Wk   = (const float*)d_in[4];
    const float* bk   = (const float*)d_in[5];
    const float* Wv   = (const float*)d_in[6];
    const float* bv   = (const float*)d_in[7];
    const float* pW1  = (const float*)d_in[8];
    const float* pb1  = (const float*)d_in[9];
    const float* pg1  = (const float*)d_in[10];
    const float* pbe1 = (const float*)d_in[11];
    const float* pW2  = (const float*)d_in[12];
    const float* pb2  = (const float*)d_in[13];
    const float* pg2  = (const float*)d_in[14];
    const float* pbe2 = (const float*)d_in[15];
    const float* aW1  = (const float*)d_in[16];
    const float* ab1  = (const float*)d_in[17];
    const float* ag1  = (const float*)d_in[18];
    const float* abe1 = (const float*)d_in[19];
    const float* aW2  = (const float*)d_in[20];
    const float* ab2  = (const float*)d_in[21];
    const float* ag2  = (const float*)d_in[22];
    const float* abe2 = (const float*)d_in[23];
    const int* fps_idx = (const int*)d_in[24];
    float* out = (float*)d_out;

    char* ws = (char*)d_ws;
    size_t off = 0;
    auto alloc = [&](size_t bytes) -> void* {
        void* r = ws + off;
        off = (off + bytes + 255) & ~(size_t)255;
        return r;
    };
    float* gacc    = (float*)alloc(160*68*4);        // zeroed
    float* posmom  = (float*)alloc(8*9*4);           // zeroed
    float* stats32 = (float*)alloc(3*32*256*4);      // zeroed
    size_t zero_bytes = off;
    float* w3  = (float*)alloc(4*128*4);
    float* CqT = (float*)alloc(64*128*4);
    float* CkT = (float*)alloc(64*128*4);
    float* dq  = (float*)alloc(128*4);
    float* dk  = (float*)alloc(128*4);
    float* WvT = (float*)alloc(64*128*4);
    u16* Wb0   = (u16*)alloc(128*128*2);
    u16* Wb1   = (u16*)alloc(128*128*2);
    u16* Wb2   = (u16*)alloc(128*128*2);
    float* Aq2 = (float*)alloc((size_t)N_*128*4);
    float* Ak2 = (float*)alloc(160*128*4);
    float* xv  = (float*)alloc(160*128*4);
    u16* bigA  = (u16*)alloc((size_t)E_*128*2);      // z2
    u16* bigB  = (u16*)alloc((size_t)E_*128*2);      // za1 -> za2 (in place)

    hipMemsetAsync(d_ws, 0, zero_bytes, stream);

    prep_weights<<<69, 256, 0, stream>>>(Wq, bq, Wk, bk, aW1, ab1, pW2, aW2, Wv,
                                         CqT, CkT, dq, dk, WvT, Wb0, Wb1, Wb2);
    knn_scatter<<<256, 256, 0, stream>>>(pos, x, fps_idx, gacc, posmom);
    proj_m<<<160, 128, 0, stream>>>(gacc, CkT, dk, WvT, bv, Ak2, xv);
    bn1_prep<<<1, 256, 0, stream>>>(gacc, posmom, pW1, pb1, pg1, pbe1, w3);
    proj_q<<<N_/8, 256, 0, stream>>>(x, CqT, dq, Aq2);

    float* stA = stats32;
    float* stB = stats32 + 32*256;
    float* stC = stats32 + 2*32*256;

    // gemm1: rel -> z2 (bias pb2), stats -> stA
    gemm_fused<0><<<E_/128, 256, 0, stream>>>(nullptr, bigA, Wb0,
        nullptr, nullptr, nullptr, w3, pb2, nullptr, nullptr, pos, gacc, stA);

    // gemm2: z2 -> za1 (+Aq2-Ak2), BN2 inline from stA, stats -> stB
    gemm_fused<1><<<E_/128, 256, 0, stream>>>(bigA, bigB, Wb1,
        stA, pg2, pbe2, nullptr, nullptr, Aq2, Ak2, nullptr, nullptr, stB);

    // gemm3: za1 -> za2 in place (bias ab2), BN3 inline from stB, stats -> stC
    gemm_fused<2><<<E_/128, 256, 0, stream>>>(bigB, bigB, Wb2,
        stB, ag1, abe1, nullptr, ab2, nullptr, nullptr, nullptr, nullptr, stC);

    // final: BN2 (stA) for delta, BN4 (stC) for alpha
    final_kernel<<<N_/4, 256, 0, stream>>>(bigA, bigB,
        stA, pg2, pbe2, stC, ag2, abe2, xv, out);
}

// Round 10
// 326.396 us; speedup vs baseline: 1.5047x; 1.1211x over previous
//
#include <hip/hip_runtime.h>
#include <hip/hip_bf16.h>
#include <stdint.h>

#define B_ 8
#define P_ 2048
#define K_ 20
#define N_ (B_*P_)     // 16384
#define M_ (B_*K_)     // 160
#define C 128
#define E_ (N_*K_)     // 327680
#define EPS_ 1e-5f

typedef unsigned short u16;
typedef unsigned int u32;
typedef __attribute__((ext_vector_type(8))) short short8;
typedef __attribute__((ext_vector_type(4))) float floatx4;

__device__ __forceinline__ float bf2f(u16 u){
    union { u32 i; float f; } v; v.i = ((u32)u) << 16; return v.f;
}
__device__ __forceinline__ u16 f2bf(float f){
    union { float f; u32 i; } v; v.f = f;
    u32 r = ((v.i >> 16) & 1u) + 0x7fffu;
    return (u16)((v.i + r) >> 16);
}
__device__ __forceinline__ u32 pkbf(float a, float b){
    union { __hip_bfloat162 h; u32 u; } cv;
    cv.h = __float22bfloat162_rn(make_float2(a, b));
    return cv.u;
}

// ---------------------------------------------------------------------------
// prep: CqT = (aW1@Wq)^T [64,128], CkT = (aW1@Wk)^T, dq = aW1@bq + ab1,
//       dk = aW1@bk, WvT [64,128], frag-major bf16 copies of pW2, aW1, aW2.
// grid 69 x 256
__global__ __launch_bounds__(256)
void prep_weights(const float* __restrict__ Wq, const float* __restrict__ bq,
                  const float* __restrict__ Wk, const float* __restrict__ bk,
                  const float* __restrict__ aW1, const float* __restrict__ ab1,
                  const float* __restrict__ pW2, const float* __restrict__ aW2,
                  const float* __restrict__ Wv,
                  float* __restrict__ CqT, float* __restrict__ CkT,
                  float* __restrict__ dq, float* __restrict__ dk,
                  float* __restrict__ WvT,
                  u16* __restrict__ Wb0, u16* __restrict__ Wb1, u16* __restrict__ Wb2)
{
    int tid = threadIdx.x, blk = blockIdx.x;
    if (blk < 32) {
        int idx = blk*256 + tid; int o = idx >> 6, i = idx & 63;
        float s = 0.f;
        for (int cc = 0; cc < 128; ++cc) s = fmaf(aW1[o*128+cc], Wq[cc*64+i], s);
        CqT[i*128 + o] = s;
    } else if (blk < 64) {
        int idx = (blk-32)*256 + tid; int o = idx >> 6, i = idx & 63;
        float s = 0.f;
        for (int cc = 0; cc < 128; ++cc) s = fmaf(aW1[o*128+cc], Wk[cc*64+i], s);
        CkT[i*128 + o] = s;
    } else if (blk == 64) {
        if (tid < 128) {
            float s = ab1[tid];
            for (int cc = 0; cc < 128; ++cc) s = fmaf(aW1[tid*128+cc], bq[cc], s);
            dq[tid] = s;
        } else {
            int o = tid - 128;
            float s = 0.f;
            for (int cc = 0; cc < 128; ++cc) s = fmaf(aW1[o*128+cc], bk[cc], s);
            dk[o] = s;
        }
    } else if (blk == 68) {
        for (int idx = tid; idx < 8192; idx += 256) {
            int o = idx >> 6, i = idx & 63;
            WvT[i*128 + o] = Wv[idx];
        }
    } else {
        // frag-major remap: slot s = (ct*4+ks)*64 + lane, 8 u16 per slot.
        const float* src = (blk == 65) ? pW2 : (blk == 66) ? aW1 : aW2;
        u16* dst = (blk == 65) ? Wb0 : (blk == 66) ? Wb1 : Wb2;
        for (int s = tid; s < 2048; s += 256) {
            int ln = s & 63, ks = (s >> 6) & 3, ct = s >> 8;
            int Ls = ln & 15, qs = ln >> 4;
            const float* sp = src + (ct*16+Ls)*C + ks*32 + qs*8;
            #pragma unroll
            for (int j = 0; j < 8; ++j) dst[s*8+j] = f2bf(sp[j]);
        }
    }
}

// ---------------------------------------------------------------------------
// knn + kernel-weighted scatter into gacc[m][68] + per-graph pos moments.
// grid 256 x 256
__global__ __launch_bounds__(256)
void knn_scatter(const float* __restrict__ pos, const float* __restrict__ x,
                 const int* __restrict__ fps_idx, float* __restrict__ gacc,
                 float* __restrict__ posmom)
{
    __shared__ float fpos[K_][3];
    __shared__ float accL[K_*68];
    __shared__ int   skb[64];
    __shared__ float sek[64];
    int tid = threadIdx.x;
    int b = blockIdx.x >> 5;              // 32 blocks per graph
    if (tid < K_*3) {
        int k = tid / 3, d = tid - k*3;
        fpos[k][d] = pos[fps_idx[b*K_+k]*3 + d];
    }
    for (int i = tid; i < K_*68; i += 256) accL[i] = 0.f;
    __syncthreads();

    int wbase = blockIdx.x*64;
    if (tid < 64) {
        int p = wbase + tid;
        float px = pos[p*3], py = pos[p*3+1], pz = pos[p*3+2];
        float best = 1e30f; int kb = 0;
        #pragma unroll
        for (int k = 0; k < K_; ++k) {
            float dx = px - fpos[k][0], dy = py - fpos[k][1], dz = pz - fpos[k][2];
            float d2 = dx*dx + dy*dy + dz*dz;
            if (d2 < best) { best = d2; kb = k; }   // strict <: argmin keeps first
        }
        float ek = 1.0f / (1.0f + 5.0f*best);
        skb[tid] = kb; sek[tid] = ek;
        atomicAdd(&accL[kb*68 + 0], 1.0f);
        atomicAdd(&accL[kb*68 + 1], ek*px);
        atomicAdd(&accL[kb*68 + 2], ek*py);
        atomicAdd(&accL[kb*68 + 3], ek*pz);

        float mom[9] = {px,py,pz, px*px,px*py,px*pz, py*py,py*pz, pz*pz};
        #pragma unroll
        for (int i = 0; i < 9; ++i) {
            float v = mom[i];
            v += __shfl_xor(v,32); v += __shfl_xor(v,16); v += __shfl_xor(v,8);
            v += __shfl_xor(v,4);  v += __shfl_xor(v,2);  v += __shfl_xor(v,1);
            mom[i] = v;
        }
        if (tid == 0) {
            #pragma unroll
            for (int i = 0; i < 9; ++i) atomicAdd(&posmom[b*9+i], mom[i]);
        }
    }
    __syncthreads();

    int w = tid >> 6, lane = tid & 63;
    #pragma unroll
    for (int jj = 0; jj < 16; ++jj) {
        int j = w*16 + jj;
        int   kbj = skb[j];
        float ekj = sek[j];
        float xvv = x[(size_t)(wbase+j)*64 + lane];
        atomicAdd(&accL[kbj*68 + 4 + lane], ekj*xvv);
    }
    __syncthreads();
    for (int i = tid; i < K_*68; i += 256)
        atomicAdd(&gacc[b*K_*68 + i], accL[i]);
}

// ---------------------------------------------------------------------------
// proj_m + fps divide: divides gacc row m in place (for bn1_prep & gemm1),
// then Ak2[m] = Ck@fps_x + dk ; xv[m] = Wv@fps_x + bv. grid 160 x 128
__global__ __launch_bounds__(128)
void proj_m(float* __restrict__ gacc, const float* __restrict__ CkT,
            const float* __restrict__ dk, const float* __restrict__ WvT,
            const float* __restrict__ bv, float* __restrict__ Ak2,
            float* __restrict__ xv)
{
    __shared__ float sfx[68];
    int m = blockIdx.x, o = threadIdx.x;
    if (o < 68) {
        float c = gacc[m*68];
        float inv = 1.0f / (c > 1.f ? c : 1.f);
        float vdiv = (o >= 1) ? gacc[m*68+o]*inv : c;
        sfx[o] = vdiv;
        if (o >= 1) gacc[m*68+o] = vdiv;
    }
    __syncthreads();
    float a = dk[o], v = bv[o];
    for (int i = 0; i < 64; ++i) {
        float xi = sfx[4+i];
        a = fmaf(CkT[i*128+o], xi, a);
        v = fmaf(WvT[i*128+o], xi, v);
    }
    Ak2[m*C+o] = a; xv[m*C+o] = v;
}

// ---------------------------------------------------------------------------
// closed-form BN1 stats from rel moments; fold BN1+pW1 -> w3[4][128].
// reads DIVIDED gacc (proj_m runs first). single block x 256
__global__ __launch_bounds__(256)
void bn1_prep(const float* __restrict__ gacc, const float* __restrict__ posmom,
              const float* __restrict__ pW1, const float* __restrict__ pb1,
              const float* __restrict__ pg1, const float* __restrict__ pbe1,
              float* __restrict__ w3)
{
    __shared__ float sF[8][3], sG[8][6];
    __shared__ float S1[3], S2[6];
    int t = threadIdx.x;
    if (t < 8) {
        float F0=0,F1=0,F2=0,G0=0,G1=0,G2=0,G3=0,G4=0,G5=0;
        for (int k = 0; k < K_; ++k) {
            const float* f = gacc + (t*K_+k)*68 + 1;
            float x=f[0], y=f[1], z=f[2];
            F0+=x; F1+=y; F2+=z;
            G0+=x*x; G1+=x*y; G2+=x*z; G3+=y*y; G4+=y*z; G5+=z*z;
        }
        sF[t][0]=F0; sF[t][1]=F1; sF[t][2]=F2;
        sG[t][0]=G0; sG[t][1]=G1; sG[t][2]=G2; sG[t][3]=G3; sG[t][4]=G4; sG[t][5]=G5;
    }
    __syncthreads();
    if (t == 0) {
        float s1[3]={0,0,0}, s2[6]={0,0,0,0,0,0};
        for (int b = 0; b < 8; ++b) {
            const float* pm = posmom + b*9;
            float Ax=pm[0],Ay=pm[1],Az=pm[2];
            float Fx=sF[b][0],Fy=sF[b][1],Fz=sF[b][2];
            s1[0] += (float)K_*Ax - (float)P_*Fx;
            s1[1] += (float)K_*Ay - (float)P_*Fy;
            s1[2] += (float)K_*Az - (float)P_*Fz;
            s2[0] += (float)K_*pm[3] - 2.f*Ax*Fx + (float)P_*sG[b][0];
            s2[1] += (float)K_*pm[4] - Ax*Fy - Ay*Fx + (float)P_*sG[b][1];
            s2[2] += (float)K_*pm[5] - Ax*Fz - Az*Fx + (float)P_*sG[b][2];
            s2[3] += (float)K_*pm[6] - 2.f*Ay*Fy + (float)P_*sG[b][3];
            s2[4] += (float)K_*pm[7] - Ay*Fz - Az*Fy + (float)P_*sG[b][4];
            s2[5] += (float)K_*pm[8] - 2.f*Az*Fz + (float)P_*sG[b][5];
        }
        for (int i = 0; i < 3; ++i) S1[i] = s1[i];
        for (int i = 0; i < 6; ++i) S2[i] = s2[i];
    }
    __syncthreads();
    if (t < 128) {
        float w0=pW1[t*3], w1=pW1[t*3+1], w2=pW1[t*3+2], bb=pb1[t];
        float wS1 = w0*S1[0] + w1*S1[1] + w2*S1[2];
        float wS2w = w0*w0*S2[0] + w1*w1*S2[3] + w2*w2*S2[5]
                   + 2.f*(w0*w1*S2[1] + w0*w2*S2[2] + w1*w2*S2[4]);
        const float invE = 1.0f/(float)E_;
        float m1  = wS1*invE + bb;
        float Ez2 = (wS2w + 2.f*bb*wS1)*invE + bb*bb;
        float var = Ez2 - m1*m1;
        float sc = pg1[t] * rsqrtf(var + EPS_);
        float sh = pbe1[t] - m1*sc;
        w3[0*128+t] = w0*sc; w3[1*128+t] = w1*sc;
        w3[2*128+t] = w2*sc; w3[3*128+t] = bb*sc + sh;
    }
}

// Aq2[p] = CqT^T@x[p] + dq. 8 points/block. grid 2048 x 256
__global__ __launch_bounds__(256)
void proj_q(const float* __restrict__ x, const float* __restrict__ CqT,
            const float* __restrict__ dq, float* __restrict__ Aq2)
{
    __shared__ float xs[512];
    int tid = threadIdx.x;
    int p0 = blockIdx.x*8;
    const float* xp = x + (size_t)p0*64;
    for (int i = tid; i < 512; i += 256) xs[i] = xp[i];
    __syncthreads();
    int g = tid >> 7, o = tid & 127;
    const float* xb = xs + g*256;
    float d = dq[o];
    float a0=d, a1=d, a2=d, a3=d;
    #pragma unroll 4
    for (int i = 0; i < 64; ++i) {
        float w = CqT[i*128 + o];
        a0 = fmaf(w, xb[i],       a0);
        a1 = fmaf(w, xb[64+i],    a1);
        a2 = fmaf(w, xb[128+i],   a2);
        a3 = fmaf(w, xb[192+i],   a3);
    }
    int pb = p0 + g*4;
    Aq2[(size_t)(pb+0)*C + o] = a0;
    Aq2[(size_t)(pb+1)*C + o] = a1;
    Aq2[(size_t)(pb+2)*C + o] = a2;
    Aq2[(size_t)(pb+3)*C + o] = a3;
}

// ---------------------------------------------------------------------------
// Fused GEMM (R5 structure + inline BN prologue, PLAIN stores):
// 2 tiles/wave, no hot-loop barriers, fused output stats into 32-way
// replicated global accumulators.
// MODE 0: A = BN1-folded pos-MLP layer1 on the fly; +bias(pb2); store z2
// MODE 1: A = relu(zin*sc+sh) [BN from statsin]; +Aq2[p]-Ak2[m]; store za1
// MODE 2: A = relu(zin*sc+sh) [BN from statsin]; +bias(ab2); store za2
// grid 2560 x 256
template<int MODE>
__global__ __launch_bounds__(256)
void gemm_fused(const u16* __restrict__ zin, u16* __restrict__ zout,
                const u16* __restrict__ Wbf,
                const float* __restrict__ statsin, const float* __restrict__ g,
                const float* __restrict__ be,
                const float* __restrict__ w3, const float* __restrict__ bias,
                const float* __restrict__ rowq, const float* __restrict__ rowk,
                const float* __restrict__ pos, const float* __restrict__ gacc,
                float* __restrict__ stats32)
{
    __shared__ float s_stat[2][C];
    __shared__ float saff[5*C];

    int tid = threadIdx.x;
    const int wave = tid >> 6, lane = tid & 63;
    const int L = lane & 15, q = lane >> 4;

    ((float*)s_stat)[tid] = 0.f;
    if constexpr (MODE == 0) {
        for (int i = tid; i < 512; i += 256) saff[i] = w3[i];
        if (tid < C) saff[512+tid] = bias[tid];
    } else {
        if (tid < C) {
            float s = 0.f, sq = 0.f;
            for (int r = 0; r < 32; ++r) {
                s  += statsin[r*256 + tid];
                sq += statsin[r*256 + 128 + tid];
            }
            float mean = s*(1.0f/E_), var = sq*(1.0f/E_) - mean*mean;
            float sc = g[tid] * rsqrtf(var + EPS_);
            saff[tid] = sc; saff[C+tid] = be[tid] - mean*sc;
        }
        if constexpr (MODE == 2) {
            if (tid >= 128) saff[2*C + tid - 128] = bias[tid - 128];
        }
    }
    __syncthreads();

    int tbs[2];
    tbs[0] = (blockIdx.x*8 + wave)*16;
    tbs[1] = (blockIdx.x*8 + wave + 4)*16;

    short8 An[2][4];
    float rr0[2], rr1[2], rr2[2];
    #pragma unroll
    for (int tt = 0; tt < 2; ++tt) {
        if constexpr (MODE != 0) {
            const u16* ap = zin + (size_t)(tbs[tt] + L)*C + q*8;
            An[tt][0] = *(const short8*)ap;
            An[tt][1] = *(const short8*)(ap + 32);
            An[tt][2] = *(const short8*)(ap + 64);
            An[tt][3] = *(const short8*)(ap + 96);
        } else {
            unsigned e = (unsigned)(tbs[tt] + L);
            unsigned p = e / 20u; int k = (int)(e - p*20u);
            int m = (int)(p >> 11)*20 + k;
            const float* fp = gacc + m*68 + 1;
            rr0[tt] = pos[p*3]   - fp[0];
            rr1[tt] = pos[p*3+1] - fp[1];
            rr2[tt] = pos[p*3+2] - fp[2];
        }
    }

    floatx4 acc[2][8];
    #pragma unroll
    for (int tt = 0; tt < 2; ++tt)
        #pragma unroll
        for (int ct = 0; ct < 8; ++ct) acc[tt][ct] = (floatx4){0.f,0.f,0.f,0.f};

    #pragma unroll
    for (int ks = 0; ks < 4; ++ks) {
        int ch0 = ks*32 + q*8;
        short8 bfr[8];
        #pragma unroll
        for (int ct = 0; ct < 8; ++ct)
            bfr[ct] = *(const short8*)(Wbf + ((ct*4+ks)*64 + lane)*8);
        #pragma unroll
        for (int tt = 0; tt < 2; ++tt) {
            union { short8 s8; u32 u[4]; } af;
            if constexpr (MODE == 0) {
                #pragma unroll
                for (int jj = 0; jj < 4; ++jj) {
                    int c0 = ch0 + jj*2, c1 = ch0 + jj*2 + 1;
                    float f0 = fmaf(saff[c0], rr0[tt], fmaf(saff[C+c0], rr1[tt],
                               fmaf(saff[2*C+c0], rr2[tt], saff[3*C+c0])));
                    float f1 = fmaf(saff[c1], rr0[tt], fmaf(saff[C+c1], rr1[tt],
                               fmaf(saff[2*C+c1], rr2[tt], saff[3*C+c1])));
                    f0 = f0 > 0.f ? f0 : 0.f;
                    f1 = f1 > 0.f ? f1 : 0.f;
                    af.u[jj] = pkbf(f0, f1);
                }
            } else {
                short8 ar = An[tt][ks];
                #pragma unroll
                for (int jj = 0; jj < 4; ++jj) {
                    int c0 = ch0 + jj*2, c1 = ch0 + jj*2 + 1;
                    float f0 = fmaf(bf2f((u16)ar[jj*2]),   saff[c0], saff[C+c0]);
                    float f1 = fmaf(bf2f((u16)ar[jj*2+1]), saff[c1], saff[C+c1]);
                    f0 = f0 > 0.f ? f0 : 0.f;
                    f1 = f1 > 0.f ? f1 : 0.f;
                    af.u[jj] = pkbf(f0, f1);
                }
            }
            #pragma unroll
            for (int ct = 0; ct < 8; ++ct)
                acc[tt][ct] = __builtin_amdgcn_mfma_f32_16x16x32_bf16(af.s8, bfr[ct], acc[tt][ct], 0, 0, 0);
        }
    }

    float ssum[8], ssq[8];
    #pragma unroll
    for (int i = 0; i < 8; ++i) { ssum[i] = 0.f; ssq[i] = 0.f; }

    #pragma unroll
    for (int tt = 0; tt < 2; ++tt) {
        const int tilebase = tbs[tt];
        int pp[4], mm[4];
        if constexpr (MODE == 1) {
            #pragma unroll
            for (int r = 0; r < 4; ++r) {
                unsigned e2 = (unsigned)(tilebase + q*4 + r);
                unsigned p2 = e2 / 20u; int k2 = (int)(e2 - p2*20u);
                pp[r] = (int)p2; mm[r] = (int)(p2 >> 11)*20 + k2;
            }
        }
        u16* orow = zout + (size_t)(tilebase + q*4)*C + L;
        #pragma unroll
        for (int ct = 0; ct < 8; ++ct) {
            int col = ct*16 + L;
            float bb;
            if constexpr (MODE == 0) bb = saff[4*C + col];
            else if constexpr (MODE == 2) bb = saff[2*C + col];
            else bb = 0.f;
            #pragma unroll
            for (int r = 0; r < 4; ++r) {
                float z = acc[tt][ct][r] + bb;
                if constexpr (MODE == 1)
                    z += rowq[pp[r]*C + col] - rowk[mm[r]*C + col];
                ssum[ct] += z; ssq[ct] += z*z;
                orow[(size_t)r*C + ct*16] = (u16)pkbf(z, z);
            }
        }
    }

    #pragma unroll
    for (int ct = 0; ct < 8; ++ct) {
        float v = ssum[ct]; v += __shfl_xor(v,16); v += __shfl_xor(v,32);
        float w = ssq[ct];  w += __shfl_xor(w,16); w += __shfl_xor(w,32);
        if (lane < 16) {
            atomicAdd(&s_stat[0][ct*16+L], v);
            atomicAdd(&s_stat[1][ct*16+L], w);
        }
    }
    __syncthreads();
    float* dst = stats32 + ((blockIdx.x & 31) << 8);
    atomicAdd(&dst[tid], ((float*)s_stat)[tid]);
}

// ---------------------------------------------------------------------------
// final: alpha = softmax_k(relu(BN4(za2))); delta = relu(BN2(z2));
// out[p,c] = sum_k alpha*(xv[m,c]+delta). BN2/BN4 affines reduced inline
// from raw stat replicas. 2 points per wave (independent chains, shared xv),
// 2 channels/lane, 8 points/block. grid 2048 x 256
__global__ __launch_bounds__(256)
void final_kernel(const u16* __restrict__ z2, const u16* __restrict__ za2,
                  const float* __restrict__ stA, const float* __restrict__ pg2,
                  const float* __restrict__ pbe2,
                  const float* __restrict__ stC, const float* __restrict__ ag2,
                  const float* __restrict__ abe2,
                  const float* __restrict__ xv, float* __restrict__ out)
{
    __shared__ float saff[4*C];   // sc2, sh2, sc4, sh4
    int tid = threadIdx.x;
    if (tid < C) {
        float s=0.f, sq=0.f;
        for (int r = 0; r < 32; ++r) { s += stA[r*256+tid]; sq += stA[r*256+128+tid]; }
        float mean = s*(1.0f/E_), var = sq*(1.0f/E_)-mean*mean;
        float sc = pg2[tid]*rsqrtf(var+EPS_);
        saff[tid] = sc; saff[C+tid] = pbe2[tid]-mean*sc;
    } else {
        int c = tid - C;
        float s=0.f, sq=0.f;
        for (int r = 0; r < 32; ++r) { s += stC[r*256+c]; sq += stC[r*256+128+c]; }
        float mean = s*(1.0f/E_), var = sq*(1.0f/E_)-mean*mean;
        float sc = ag2[c]*rsqrtf(var+EPS_);
        saff[2*C+c] = sc; saff[3*C+c] = abe2[c]-mean*sc;
    }
    __syncthreads();

    int wave = tid >> 6, lane = tid & 63;
    int p0 = blockIdx.x*8 + wave*2;      // two points: p0, p0+1 (same graph)
    int c2 = lane*2;
    int b = p0 >> 11;
    float S2x=saff[c2], S2y=saff[c2+1], H2x=saff[C+c2], H2y=saff[C+c2+1];
    float S4x=saff[2*C+c2], S4y=saff[2*C+c2+1], H4x=saff[3*C+c2], H4y=saff[3*C+c2+1];
    size_t eb0 = (size_t)p0 * K_;
    size_t eb1 = eb0 + K_;
    const float* xvb = xv + (size_t)(b*K_)*C + c2;
    float l0a=0.f, l1a=0.f, o0a=0.f, o1a=0.f;
    float l0b=0.f, l1b=0.f, o0b=0.f, o1b=0.f;
    #pragma unroll
    for (int k = 0; k < K_; ++k) {
        u32 waA = *(const u32*)(za2 + (eb0+k)*C + c2);
        u32 wzA = *(const u32*)(z2  + (eb0+k)*C + c2);
        u32 waB = *(const u32*)(za2 + (eb1+k)*C + c2);
        u32 wzB = *(const u32*)(z2  + (eb1+k)*C + c2);
        float2 xvv = *(const float2*)(xvb + (size_t)k*C);
        // point A
        float aa0 = fmaf(bf2f((u16)(waA & 0xffffu)), S4x, H4x); aa0 = aa0 > 0.f ? aa0 : 0.f;
        float aa1 = fmaf(bf2f((u16)(waA >> 16)),     S4y, H4y); aa1 = aa1 > 0.f ? aa1 : 0.f;
        float dd0 = fmaf(bf2f((u16)(wzA & 0xffffu)), S2x, H2x); dd0 = dd0 > 0.f ? dd0 : 0.f;
        float dd1 = fmaf(bf2f((u16)(wzA >> 16)),     S2y, H2y); dd1 = dd1 > 0.f ? dd1 : 0.f;
        float e0 = __expf(aa0), e1 = __expf(aa1);
        l0a += e0; l1a += e1;
        o0a = fmaf(e0, xvv.x + dd0, o0a);
        o1a = fmaf(e1, xvv.y + dd1, o1a);
        // point B
        float ba0 = fmaf(bf2f((u16)(waB & 0xffffu)), S4x, H4x); ba0 = ba0 > 0.f ? ba0 : 0.f;
        float ba1 = fmaf(bf2f((u16)(waB >> 16)),     S4y, H4y); ba1 = ba1 > 0.f ? ba1 : 0.f;
        float bd0 = fmaf(bf2f((u16)(wzB & 0xffffu)), S2x, H2x); bd0 = bd0 > 0.f ? bd0 : 0.f;
        float bd1 = fmaf(bf2f((u16)(wzB >> 16)),     S2y, H2y); bd1 = bd1 > 0.f ? bd1 : 0.f;
        float f0 = __expf(ba0), f1 = __expf(ba1);
        l0b += f0; l1b += f1;
        o0b = fmaf(f0, xvv.x + bd0, o0b);
        o1b = fmaf(f1, xvv.y + bd1, o1b);
    }
    out[(size_t)p0*C + c2]       = o0a / l0a;
    out[(size_t)p0*C + c2 + 1]   = o1a / l1a;
    out[(size_t)(p0+1)*C + c2]     = o0b / l0b;
    out[(size_t)(p0+1)*C + c2 + 1] = o1b / l1b;
}

// ---------------------------------------------------------------------------
extern "C" void kernel_launch(void* const* d_in, const int* in_sizes, int n_in,
                              void* d_out, int out_size, void* d_ws, size_t ws_size,
                              hipStream_t stream)
{
    const float* x    = (const float*)d_in[0];
    const float* pos  = (const float*)d_in[1];
    const float* Wq   = (const float*)d_in[2];
    const float* bq   = (const float*)d_in[3];
    const float* Wk   = (const float*)d_in[4];
    const float* bk   = (const float*)d_in[5];
    const float* Wv   = (const float*)d_in[6];
    const float* bv   = (const float*)d_in[7];
    const float* pW1  = (const float*)d_in[8];
    const float* pb1  = (const float*)d_in[9];
    const float* pg1  = (const float*)d_in[10];
    const float* pbe1 = (const float*)d_in[11];
    const float* pW2  = (const float*)d_in[12];
    const float* pb2  = (const float*)d_in[13];
    const float* pg2  = (const float*)d_in[14];
    const float* pbe2 = (const float*)d_in[15];
    const float* aW1  = (const float*)d_in[16];
    const float* ab1  = (const float*)d_in[17];
    const float* ag1  = (const float*)d_in[18];
    const float* abe1 = (const float*)d_in[19];
    const float* aW2  = (const float*)d_in[20];
    const float* ab2  = (const float*)d_in[21];
    const float* ag2  = (const float*)d_in[22];
    const float* abe2 = (const float*)d_in[23];
    const int* fps_idx = (const int*)d_in[24];
    float* out = (float*)d_out;

    char* ws = (char*)d_ws;
    size_t off = 0;
    auto alloc = [&](size_t bytes) -> void* {
        void* r = ws + off;
        off = (off + bytes + 255) & ~(size_t)255;
        return r;
    };
    float* gacc    = (float*)alloc(160*68*4);        // zeroed
    float* posmom  = (float*)alloc(8*9*4);           // zeroed
    float* stats32 = (float*)alloc(3*32*256*4);      // zeroed
    size_t zero_bytes = off;
    float* w3  = (float*)alloc(4*128*4);
    float* CqT = (float*)alloc(64*128*4);
    float* CkT = (float*)alloc(64*128*4);
    float* dq  = (float*)alloc(128*4);
    float* dk  = (float*)alloc(128*4);
    float* WvT = (float*)alloc(64*128*4);
    u16* Wb0   = (u16*)alloc(128*128*2);
    u16* Wb1   = (u16*)alloc(128*128*2);
    u16* Wb2   = (u16*)alloc(128*128*2);
    float* Aq2 = (float*)alloc((size_t)N_*128*4);
    float* Ak2 = (float*)alloc(160*128*4);
    float* xv  = (float*)alloc(160*128*4);
    u16* bigA  = (u16*)alloc((size_t)E_*128*2);      // z2
    u16* bigB  = (u16*)alloc((size_t)E_*128*2);      // za1 -> za2 (in place)

    hipMemsetAsync(d_ws, 0, zero_bytes, stream);

    prep_weights<<<69, 256, 0, stream>>>(Wq, bq, Wk, bk, aW1, ab1, pW2, aW2, Wv,
                                         CqT, CkT, dq, dk, WvT, Wb0, Wb1, Wb2);
    knn_scatter<<<256, 256, 0, stream>>>(pos, x, fps_idx, gacc, posmom);
    proj_m<<<160, 128, 0, stream>>>(gacc, CkT, dk, WvT, bv, Ak2, xv);
    bn1_prep<<<1, 256, 0, stream>>>(gacc, posmom, pW1, pb1, pg1, pbe1, w3);
    proj_q<<<N_/8, 256, 0, stream>>>(x, CqT, dq, Aq2);

    float* stA = stats32;
    float* stB = stats32 + 32*256;
    float* stC = stats32 + 2*32*256;

    // gemm1: rel -> z2 (bias pb2), stats -> stA
    gemm_fused<0><<<E_/128, 256, 0, stream>>>(nullptr, bigA, Wb0,
        nullptr, nullptr, nullptr, w3, pb2, nullptr, nullptr, pos, gacc, stA);

    // gemm2: z2 -> za1 (+Aq2-Ak2), BN2 inline from stA, stats -> stB
    gemm_fused<1><<<E_/128, 256, 0, stream>>>(bigA, bigB, Wb1,
        stA, pg2, pbe2, nullptr, nullptr, Aq2, Ak2, nullptr, nullptr, stB);

    // gemm3: za1 -> za2 in place (bias ab2), BN3 inline from stB, stats -> stC
    gemm_fused<2><<<E_/128, 256, 0, stream>>>(bigB, bigB, Wb2,
        stB, ag1, abe1, nullptr, ab2, nullptr, nullptr, nullptr, nullptr, stC);

    // final: BN2 (stA) for delta, BN4 (stC) for alpha
    final_kernel<<<N_/8, 256, 0, stream>>>(bigA, bigB,
        stA, pg2, pbe2, stC, ag2, abe2, xv, out);
}

// Round 11
// 313.761 us; speedup vs baseline: 1.5653x; 1.0403x over previous
//
#include <hip/hip_runtime.h>
#include <hip/hip_bf16.h>
#include <stdint.h>

#define B_ 8
#define P_ 2048
#define K_ 20
#define N_ (B_*P_)     // 16384
#define M_ (B_*K_)     // 160
#define C 128
#define E_ (N_*K_)     // 327680
#define EPS_ 1e-5f

typedef unsigned short u16;
typedef unsigned int u32;
typedef __attribute__((ext_vector_type(8))) short short8;
typedef __attribute__((ext_vector_type(4))) float floatx4;

__device__ __forceinline__ float bf2f(u16 u){
    union { u32 i; float f; } v; v.i = ((u32)u) << 16; return v.f;
}
__device__ __forceinline__ u16 f2bf(float f){
    union { float f; u32 i; } v; v.f = f;
    u32 r = ((v.i >> 16) & 1u) + 0x7fffu;
    return (u16)((v.i + r) >> 16);
}
__device__ __forceinline__ u32 pkbf(float a, float b){
    union { __hip_bfloat162 h; u32 u; } cv;
    cv.h = __float22bfloat162_rn(make_float2(a, b));
    return cv.u;
}

// ---------------------------------------------------------------------------
// prep: CqT = (aW1@Wq)^T [64,128], CkT = (aW1@Wk)^T, dq = aW1@bq + ab1,
//       dk = aW1@bk, WvT [64,128], frag-major bf16 copies of pW2, aW1, aW2.
// PERMUTED tiles: B-tile ct, colidx Ls holds output channel Ls*8+ct, so each
// lane's 8 accumulators are 8 consecutive channels (16B stores).
// grid 69 x 256
__global__ __launch_bounds__(256)
void prep_weights(const float* __restrict__ Wq, const float* __restrict__ bq,
                  const float* __restrict__ Wk, const float* __restrict__ bk,
                  const float* __restrict__ aW1, const float* __restrict__ ab1,
                  const float* __restrict__ pW2, const float* __restrict__ aW2,
                  const float* __restrict__ Wv,
                  float* __restrict__ CqT, float* __restrict__ CkT,
                  float* __restrict__ dq, float* __restrict__ dk,
                  float* __restrict__ WvT,
                  u16* __restrict__ Wb0, u16* __restrict__ Wb1, u16* __restrict__ Wb2)
{
    int tid = threadIdx.x, blk = blockIdx.x;
    if (blk < 32) {
        int idx = blk*256 + tid; int o = idx >> 6, i = idx & 63;
        float s = 0.f;
        for (int cc = 0; cc < 128; ++cc) s = fmaf(aW1[o*128+cc], Wq[cc*64+i], s);
        CqT[i*128 + o] = s;
    } else if (blk < 64) {
        int idx = (blk-32)*256 + tid; int o = idx >> 6, i = idx & 63;
        float s = 0.f;
        for (int cc = 0; cc < 128; ++cc) s = fmaf(aW1[o*128+cc], Wk[cc*64+i], s);
        CkT[i*128 + o] = s;
    } else if (blk == 64) {
        if (tid < 128) {
            float s = ab1[tid];
            for (int cc = 0; cc < 128; ++cc) s = fmaf(aW1[tid*128+cc], bq[cc], s);
            dq[tid] = s;
        } else {
            int o = tid - 128;
            float s = 0.f;
            for (int cc = 0; cc < 128; ++cc) s = fmaf(aW1[o*128+cc], bk[cc], s);
            dk[o] = s;
        }
    } else if (blk == 68) {
        for (int idx = tid; idx < 8192; idx += 256) {
            int o = idx >> 6, i = idx & 63;
            WvT[i*128 + o] = Wv[idx];
        }
    } else {
        // frag-major remap: slot s = (ct*4+ks)*64 + lane, 8 u16 per slot.
        // PERMUTED: frag element j = W[Ls*8 + ct][ks*32 + (lane>>4)*8 + j]
        const float* src = (blk == 65) ? pW2 : (blk == 66) ? aW1 : aW2;
        u16* dst = (blk == 65) ? Wb0 : (blk == 66) ? Wb1 : Wb2;
        for (int s = tid; s < 2048; s += 256) {
            int ln = s & 63, ks = (s >> 6) & 3, ct = s >> 8;
            int Ls = ln & 15, qs = ln >> 4;
            const float* sp = src + (Ls*8 + ct)*C + ks*32 + qs*8;
            #pragma unroll
            for (int j = 0; j < 8; ++j) dst[s*8+j] = f2bf(sp[j]);
        }
    }
}

// ---------------------------------------------------------------------------
// knn + kernel-weighted scatter into gacc[m][68] + per-graph pos moments.
// grid 256 x 256
__global__ __launch_bounds__(256)
void knn_scatter(const float* __restrict__ pos, const float* __restrict__ x,
                 const int* __restrict__ fps_idx, float* __restrict__ gacc,
                 float* __restrict__ posmom)
{
    __shared__ float fpos[K_][3];
    __shared__ float accL[K_*68];
    __shared__ int   skb[64];
    __shared__ float sek[64];
    int tid = threadIdx.x;
    int b = blockIdx.x >> 5;              // 32 blocks per graph
    if (tid < K_*3) {
        int k = tid / 3, d = tid - k*3;
        fpos[k][d] = pos[fps_idx[b*K_+k]*3 + d];
    }
    for (int i = tid; i < K_*68; i += 256) accL[i] = 0.f;
    __syncthreads();

    int wbase = blockIdx.x*64;
    if (tid < 64) {
        int p = wbase + tid;
        float px = pos[p*3], py = pos[p*3+1], pz = pos[p*3+2];
        float best = 1e30f; int kb = 0;
        #pragma unroll
        for (int k = 0; k < K_; ++k) {
            float dx = px - fpos[k][0], dy = py - fpos[k][1], dz = pz - fpos[k][2];
            float d2 = dx*dx + dy*dy + dz*dz;
            if (d2 < best) { best = d2; kb = k; }   // strict <: argmin keeps first
        }
        float ek = 1.0f / (1.0f + 5.0f*best);
        skb[tid] = kb; sek[tid] = ek;
        atomicAdd(&accL[kb*68 + 0], 1.0f);
        atomicAdd(&accL[kb*68 + 1], ek*px);
        atomicAdd(&accL[kb*68 + 2], ek*py);
        atomicAdd(&accL[kb*68 + 3], ek*pz);

        float mom[9] = {px,py,pz, px*px,px*py,px*pz, py*py,py*pz, pz*pz};
        #pragma unroll
        for (int i = 0; i < 9; ++i) {
            float v = mom[i];
            v += __shfl_xor(v,32); v += __shfl_xor(v,16); v += __shfl_xor(v,8);
            v += __shfl_xor(v,4);  v += __shfl_xor(v,2);  v += __shfl_xor(v,1);
            mom[i] = v;
        }
        if (tid == 0) {
            #pragma unroll
            for (int i = 0; i < 9; ++i) atomicAdd(&posmom[b*9+i], mom[i]);
        }
    }
    __syncthreads();

    int w = tid >> 6, lane = tid & 63;
    #pragma unroll
    for (int jj = 0; jj < 16; ++jj) {
        int j = w*16 + jj;
        int   kbj = skb[j];
        float ekj = sek[j];
        float xvv = x[(size_t)(wbase+j)*64 + lane];
        atomicAdd(&accL[kbj*68 + 4 + lane], ekj*xvv);
    }
    __syncthreads();
    for (int i = tid; i < K_*68; i += 256)
        atomicAdd(&gacc[b*K_*68 + i], accL[i]);
}

// ---------------------------------------------------------------------------
// proj_m + fps divide: divides gacc row m in place (for bn1_prep & gemm1),
// then Ak2[m] = Ck@fps_x + dk ; xv[m] = Wv@fps_x + bv. grid 160 x 128
__global__ __launch_bounds__(128)
void proj_m(float* __restrict__ gacc, const float* __restrict__ CkT,
            const float* __restrict__ dk, const float* __restrict__ WvT,
            const float* __restrict__ bv, float* __restrict__ Ak2,
            float* __restrict__ xv)
{
    __shared__ float sfx[68];
    int m = blockIdx.x, o = threadIdx.x;
    if (o < 68) {
        float c = gacc[m*68];
        float inv = 1.0f / (c > 1.f ? c : 1.f);
        float vdiv = (o >= 1) ? gacc[m*68+o]*inv : c;
        sfx[o] = vdiv;
        if (o >= 1) gacc[m*68+o] = vdiv;
    }
    __syncthreads();
    float a = dk[o], v = bv[o];
    for (int i = 0; i < 64; ++i) {
        float xi = sfx[4+i];
        a = fmaf(CkT[i*128+o], xi, a);
        v = fmaf(WvT[i*128+o], xi, v);
    }
    Ak2[m*C+o] = a; xv[m*C+o] = v;
}

// ---------------------------------------------------------------------------
// closed-form BN1 stats from rel moments; fold BN1+pW1 -> w3[4][128].
// reads DIVIDED gacc (proj_m runs first). single block x 256
__global__ __launch_bounds__(256)
void bn1_prep(const float* __restrict__ gacc, const float* __restrict__ posmom,
              const float* __restrict__ pW1, const float* __restrict__ pb1,
              const float* __restrict__ pg1, const float* __restrict__ pbe1,
              float* __restrict__ w3)
{
    __shared__ float sF[8][3], sG[8][6];
    __shared__ float S1[3], S2[6];
    int t = threadIdx.x;
    if (t < 8) {
        float F0=0,F1=0,F2=0,G0=0,G1=0,G2=0,G3=0,G4=0,G5=0;
        for (int k = 0; k < K_; ++k) {
            const float* f = gacc + (t*K_+k)*68 + 1;
            float x=f[0], y=f[1], z=f[2];
            F0+=x; F1+=y; F2+=z;
            G0+=x*x; G1+=x*y; G2+=x*z; G3+=y*y; G4+=y*z; G5+=z*z;
        }
        sF[t][0]=F0; sF[t][1]=F1; sF[t][2]=F2;
        sG[t][0]=G0; sG[t][1]=G1; sG[t][2]=G2; sG[t][3]=G3; sG[t][4]=G4; sG[t][5]=G5;
    }
    __syncthreads();
    if (t == 0) {
        float s1[3]={0,0,0}, s2[6]={0,0,0,0,0,0};
        for (int b = 0; b < 8; ++b) {
            const float* pm = posmom + b*9;
            float Ax=pm[0],Ay=pm[1],Az=pm[2];
            float Fx=sF[b][0],Fy=sF[b][1],Fz=sF[b][2];
            s1[0] += (float)K_*Ax - (float)P_*Fx;
            s1[1] += (float)K_*Ay - (float)P_*Fy;
            s1[2] += (float)K_*Az - (float)P_*Fz;
            s2[0] += (float)K_*pm[3] - 2.f*Ax*Fx + (float)P_*sG[b][0];
            s2[1] += (float)K_*pm[4] - Ax*Fy - Ay*Fx + (float)P_*sG[b][1];
            s2[2] += (float)K_*pm[5] - Ax*Fz - Az*Fx + (float)P_*sG[b][2];
            s2[3] += (float)K_*pm[6] - 2.f*Ay*Fy + (float)P_*sG[b][3];
            s2[4] += (float)K_*pm[7] - Ay*Fz - Az*Fy + (float)P_*sG[b][4];
            s2[5] += (float)K_*pm[8] - 2.f*Az*Fz + (float)P_*sG[b][5];
        }
        for (int i = 0; i < 3; ++i) S1[i] = s1[i];
        for (int i = 0; i < 6; ++i) S2[i] = s2[i];
    }
    __syncthreads();
    if (t < 128) {
        float w0=pW1[t*3], w1=pW1[t*3+1], w2=pW1[t*3+2], bb=pb1[t];
        float wS1 = w0*S1[0] + w1*S1[1] + w2*S1[2];
        float wS2w = w0*w0*S2[0] + w1*w1*S2[3] + w2*w2*S2[5]
                   + 2.f*(w0*w1*S2[1] + w0*w2*S2[2] + w1*w2*S2[4]);
        const float invE = 1.0f/(float)E_;
        float m1  = wS1*invE + bb;
        float Ez2 = (wS2w + 2.f*bb*wS1)*invE + bb*bb;
        float var = Ez2 - m1*m1;
        float sc = pg1[t] * rsqrtf(var + EPS_);
        float sh = pbe1[t] - m1*sc;
        w3[0*128+t] = w0*sc; w3[1*128+t] = w1*sc;
        w3[2*128+t] = w2*sc; w3[3*128+t] = bb*sc + sh;
    }
}

// Aq2[p] = CqT^T@x[p] + dq. 8 points/block. grid 2048 x 256
__global__ __launch_bounds__(256)
void proj_q(const float* __restrict__ x, const float* __restrict__ CqT,
            const float* __restrict__ dq, float* __restrict__ Aq2)
{
    __shared__ float xs[512];
    int tid = threadIdx.x;
    int p0 = blockIdx.x*8;
    const float* xp = x + (size_t)p0*64;
    for (int i = tid; i < 512; i += 256) xs[i] = xp[i];
    __syncthreads();
    int g = tid >> 7, o = tid & 127;
    const float* xb = xs + g*256;
    float d = dq[o];
    float a0=d, a1=d, a2=d, a3=d;
    #pragma unroll 4
    for (int i = 0; i < 64; ++i) {
        float w = CqT[i*128 + o];
        a0 = fmaf(w, xb[i],       a0);
        a1 = fmaf(w, xb[64+i],    a1);
        a2 = fmaf(w, xb[128+i],   a2);
        a3 = fmaf(w, xb[192+i],   a3);
    }
    int pb = p0 + g*4;
    Aq2[(size_t)(pb+0)*C + o] = a0;
    Aq2[(size_t)(pb+1)*C + o] = a1;
    Aq2[(size_t)(pb+2)*C + o] = a2;
    Aq2[(size_t)(pb+3)*C + o] = a3;
}

// ---------------------------------------------------------------------------
// Fused GEMM v7: permuted output tiles -> lane owns 8 CONSECUTIVE channels
// per row => 16B dwordx4 stores (8/wave instead of 128/wave), float4
// rowq/rowk loads. 2 tiles/wave, inline BN prologue, fused output stats.
// MODE 0: A = BN1-folded pos-MLP layer1 on the fly; +bias(pb2); store z2
// MODE 1: A = relu(zin*sc+sh) [BN from statsin]; +Aq2[p]-Ak2[m]; store za1
// MODE 2: A = relu(zin*sc+sh) [BN from statsin]; +bias(ab2); store za2
// grid 2560 x 256
template<int MODE>
__global__ __launch_bounds__(256)
void gemm_fused(const u16* __restrict__ zin, u16* __restrict__ zout,
                const u16* __restrict__ Wbf,
                const float* __restrict__ statsin, const float* __restrict__ g,
                const float* __restrict__ be,
                const float* __restrict__ w3, const float* __restrict__ bias,
                const float* __restrict__ rowq, const float* __restrict__ rowk,
                const float* __restrict__ pos, const float* __restrict__ gacc,
                float* __restrict__ stats32)
{
    __shared__ float s_stat[2][C];
    __shared__ float saff[5*C];

    int tid = threadIdx.x;
    const int wave = tid >> 6, lane = tid & 63;
    const int L = lane & 15, q = lane >> 4;

    ((float*)s_stat)[tid] = 0.f;
    if constexpr (MODE == 0) {
        for (int i = tid; i < 512; i += 256) saff[i] = w3[i];
        if (tid < C) saff[512+tid] = bias[tid];
    } else {
        if (tid < C) {
            float s = 0.f, sq = 0.f;
            for (int r = 0; r < 32; ++r) {
                s  += statsin[r*256 + tid];
                sq += statsin[r*256 + 128 + tid];
            }
            float mean = s*(1.0f/E_), var = sq*(1.0f/E_) - mean*mean;
            float sc = g[tid] * rsqrtf(var + EPS_);
            saff[tid] = sc; saff[C+tid] = be[tid] - mean*sc;
        }
        if constexpr (MODE == 2) {
            if (tid >= 128) saff[2*C + tid - 128] = bias[tid - 128];
        }
    }
    __syncthreads();

    int tbs[2];
    tbs[0] = (blockIdx.x*8 + wave)*16;
    tbs[1] = (blockIdx.x*8 + wave + 4)*16;

    short8 An[2][4];
    float rr0[2], rr1[2], rr2[2];
    #pragma unroll
    for (int tt = 0; tt < 2; ++tt) {
        if constexpr (MODE != 0) {
            const u16* ap = zin + (size_t)(tbs[tt] + L)*C + q*8;
            An[tt][0] = *(const short8*)ap;
            An[tt][1] = *(const short8*)(ap + 32);
            An[tt][2] = *(const short8*)(ap + 64);
            An[tt][3] = *(const short8*)(ap + 96);
        } else {
            unsigned e = (unsigned)(tbs[tt] + L);
            unsigned p = e / 20u; int k = (int)(e - p*20u);
            int m = (int)(p >> 11)*20 + k;
            const float* fp = gacc + m*68 + 1;
            rr0[tt] = pos[p*3]   - fp[0];
            rr1[tt] = pos[p*3+1] - fp[1];
            rr2[tt] = pos[p*3+2] - fp[2];
        }
    }

    floatx4 acc[2][8];
    #pragma unroll
    for (int tt = 0; tt < 2; ++tt)
        #pragma unroll
        for (int ct = 0; ct < 8; ++ct) acc[tt][ct] = (floatx4){0.f,0.f,0.f,0.f};

    #pragma unroll
    for (int ks = 0; ks < 4; ++ks) {
        int ch0 = ks*32 + q*8;
        short8 bfr[8];
        #pragma unroll
        for (int ct = 0; ct < 8; ++ct)
            bfr[ct] = *(const short8*)(Wbf + ((ct*4+ks)*64 + lane)*8);
        #pragma unroll
        for (int tt = 0; tt < 2; ++tt) {
            union { short8 s8; u32 u[4]; } af;
            if constexpr (MODE == 0) {
                #pragma unroll
                for (int jj = 0; jj < 4; ++jj) {
                    int c0 = ch0 + jj*2, c1 = ch0 + jj*2 + 1;
                    float f0 = fmaf(saff[c0], rr0[tt], fmaf(saff[C+c0], rr1[tt],
                               fmaf(saff[2*C+c0], rr2[tt], saff[3*C+c0])));
                    float f1 = fmaf(saff[c1], rr0[tt], fmaf(saff[C+c1], rr1[tt],
                               fmaf(saff[2*C+c1], rr2[tt], saff[3*C+c1])));
                    f0 = f0 > 0.f ? f0 : 0.f;
                    f1 = f1 > 0.f ? f1 : 0.f;
                    af.u[jj] = pkbf(f0, f1);
                }
            } else {
                short8 ar = An[tt][ks];
                #pragma unroll
                for (int jj = 0; jj < 4; ++jj) {
                    int c0 = ch0 + jj*2, c1 = ch0 + jj*2 + 1;
                    float f0 = fmaf(bf2f((u16)ar[jj*2]),   saff[c0], saff[C+c0]);
                    float f1 = fmaf(bf2f((u16)ar[jj*2+1]), saff[c1], saff[C+c1]);
                    f0 = f0 > 0.f ? f0 : 0.f;
                    f1 = f1 > 0.f ? f1 : 0.f;
                    af.u[jj] = pkbf(f0, f1);
                }
            }
            // acc[tt][j] holds output channel L*8 + j (permuted B tiles)
            #pragma unroll
            for (int ct = 0; ct < 8; ++ct)
                acc[tt][ct] = __builtin_amdgcn_mfma_f32_16x16x32_bf16(af.s8, bfr[ct], acc[tt][ct], 0, 0, 0);
        }
    }

    float ssum[8], ssq[8];
    #pragma unroll
    for (int i = 0; i < 8; ++i) { ssum[i] = 0.f; ssq[i] = 0.f; }

    #pragma unroll
    for (int tt = 0; tt < 2; ++tt) {
        const int tilebase = tbs[tt];
        int pp[4], mm[4];
        if constexpr (MODE == 1) {
            #pragma unroll
            for (int r = 0; r < 4; ++r) {
                unsigned e2 = (unsigned)(tilebase + q*4 + r);
                unsigned p2 = e2 / 20u; int k2 = (int)(e2 - p2*20u);
                pp[r] = (int)p2; mm[r] = (int)(p2 >> 11)*20 + k2;
            }
        }
        u16* orow = zout + (size_t)(tilebase + q*4)*C + L*8;
        floatx4 bb0, bb1;
        if constexpr (MODE == 0) {
            bb0 = *(const floatx4*)&saff[4*C + L*8];
            bb1 = *(const floatx4*)&saff[4*C + L*8 + 4];
        } else if constexpr (MODE == 2) {
            bb0 = *(const floatx4*)&saff[2*C + L*8];
            bb1 = *(const floatx4*)&saff[2*C + L*8 + 4];
        }
        #pragma unroll
        for (int r = 0; r < 4; ++r) {
            floatx4 z0, z1;
            #pragma unroll
            for (int j = 0; j < 4; ++j) { z0[j] = acc[tt][j][r]; z1[j] = acc[tt][4+j][r]; }
            if constexpr (MODE == 0 || MODE == 2) { z0 += bb0; z1 += bb1; }
            if constexpr (MODE == 1) {
                const float* rq = &rowq[pp[r]*C + L*8];
                const float* rk = &rowk[mm[r]*C + L*8];
                z0 += *(const floatx4*)rq - *(const floatx4*)rk;
                z1 += *(const floatx4*)(rq+4) - *(const floatx4*)(rk+4);
            }
            #pragma unroll
            for (int j = 0; j < 4; ++j) {
                ssum[j]   += z0[j]; ssq[j]   += z0[j]*z0[j];
                ssum[4+j] += z1[j]; ssq[4+j] += z1[j]*z1[j];
            }
            union { short8 s8; u32 u[4]; } ov;
            ov.u[0] = pkbf(z0[0], z0[1]);
            ov.u[1] = pkbf(z0[2], z0[3]);
            ov.u[2] = pkbf(z1[0], z1[1]);
            ov.u[3] = pkbf(z1[2], z1[3]);
            *(short8*)(orow + (size_t)r*C) = ov.s8;   // 16B store, full rows
        }
    }

    // stats: ssum[j] = channel lane*8+j partial; reduce over q-groups, then
    // the 16 L-lanes own disjoint 8-channel blocks
    #pragma unroll
    for (int j = 0; j < 8; ++j) {
        float v = ssum[j]; v += __shfl_xor(v,16); v += __shfl_xor(v,32);
        float w = ssq[j];  w += __shfl_xor(w,16); w += __shfl_xor(w,32);
        if (lane < 16) {
            atomicAdd(&s_stat[0][lane*8+j], v);
            atomicAdd(&s_stat[1][lane*8+j], w);
        }
    }
    __syncthreads();
    float* dst = stats32 + ((blockIdx.x & 31) << 8);
    atomicAdd(&dst[tid], ((float*)s_stat)[tid]);
}

// ---------------------------------------------------------------------------
// final: alpha = softmax_k(relu(BN4(za2))); delta = relu(BN2(z2));
// out[p,c] = sum_k alpha*(xv[m,c]+delta). BN2/BN4 affines reduced inline
// from raw stat replicas. 2 points per wave (independent chains, shared xv),
// 2 channels/lane, 8 points/block. grid 2048 x 256
__global__ __launch_bounds__(256)
void final_kernel(const u16* __restrict__ z2, const u16* __restrict__ za2,
                  const float* __restrict__ stA, const float* __restrict__ pg2,
                  const float* __restrict__ pbe2,
                  const float* __restrict__ stC, const float* __restrict__ ag2,
                  const float* __restrict__ abe2,
                  const float* __restrict__ xv, float* __restrict__ out)
{
    __shared__ float saff[4*C];   // sc2, sh2, sc4, sh4
    int tid = threadIdx.x;
    if (tid < C) {
        float s=0.f, sq=0.f;
        for (int r = 0; r < 32; ++r) { s += stA[r*256+tid]; sq += stA[r*256+128+tid]; }
        float mean = s*(1.0f/E_), var = sq*(1.0f/E_)-mean*mean;
        float sc = pg2[tid]*rsqrtf(var+EPS_);
        saff[tid] = sc; saff[C+tid] = pbe2[tid]-mean*sc;
    } else {
        int c = tid - C;
        float s=0.f, sq=0.f;
        for (int r = 0; r < 32; ++r) { s += stC[r*256+c]; sq += stC[r*256+128+c]; }
        float mean = s*(1.0f/E_), var = sq*(1.0f/E_)-mean*mean;
        float sc = ag2[c]*rsqrtf(var+EPS_);
        saff[2*C+c] = sc; saff[3*C+c] = abe2[c]-mean*sc;
    }
    __syncthreads();

    int wave = tid >> 6, lane = tid & 63;
    int p0 = blockIdx.x*8 + wave*2;      // two points: p0, p0+1 (same graph)
    int c2 = lane*2;
    int b = p0 >> 11;
    float S2x=saff[c2], S2y=saff[c2+1], H2x=saff[C+c2], H2y=saff[C+c2+1];
    float S4x=saff[2*C+c2], S4y=saff[2*C+c2+1], H4x=saff[3*C+c2], H4y=saff[3*C+c2+1];
    size_t eb0 = (size_t)p0 * K_;
    size_t eb1 = eb0 + K_;
    const float* xvb = xv + (size_t)(b*K_)*C + c2;
    float l0a=0.f, l1a=0.f, o0a=0.f, o1a=0.f;
    float l0b=0.f, l1b=0.f, o0b=0.f, o1b=0.f;
    #pragma unroll
    for (int k = 0; k < K_; ++k) {
        u32 waA = *(const u32*)(za2 + (eb0+k)*C + c2);
        u32 wzA = *(const u32*)(z2  + (eb0+k)*C + c2);
        u32 waB = *(const u32*)(za2 + (eb1+k)*C + c2);
        u32 wzB = *(const u32*)(z2  + (eb1+k)*C + c2);
        float2 xvv = *(const float2*)(xvb + (size_t)k*C);
        float aa0 = fmaf(bf2f((u16)(waA & 0xffffu)), S4x, H4x); aa0 = aa0 > 0.f ? aa0 : 0.f;
        float aa1 = fmaf(bf2f((u16)(waA >> 16)),     S4y, H4y); aa1 = aa1 > 0.f ? aa1 : 0.f;
        float dd0 = fmaf(bf2f((u16)(wzA & 0xffffu)), S2x, H2x); dd0 = dd0 > 0.f ? dd0 : 0.f;
        float dd1 = fmaf(bf2f((u16)(wzA >> 16)),     S2y, H2y); dd1 = dd1 > 0.f ? dd1 : 0.f;
        float e0 = __expf(aa0), e1 = __expf(aa1);
        l0a += e0; l1a += e1;
        o0a = fmaf(e0, xvv.x + dd0, o0a);
        o1a = fmaf(e1, xvv.y + dd1, o1a);
        float ba0 = fmaf(bf2f((u16)(waB & 0xffffu)), S4x, H4x); ba0 = ba0 > 0.f ? ba0 : 0.f;
        float ba1 = fmaf(bf2f((u16)(waB >> 16)),     S4y, H4y); ba1 = ba1 > 0.f ? ba1 : 0.f;
        float bd0 = fmaf(bf2f((u16)(wzB & 0xffffu)), S2x, H2x); bd0 = bd0 > 0.f ? bd0 : 0.f;
        float bd1 = fmaf(bf2f((u16)(wzB >> 16)),     S2y, H2y); bd1 = bd1 > 0.f ? bd1 : 0.f;
        float f0 = __expf(ba0), f1 = __expf(ba1);
        l0b += f0; l1b += f1;
        o0b = fmaf(f0, xvv.x + bd0, o0b);
        o1b = fmaf(f1, xvv.y + bd1, o1b);
    }
    out[(size_t)p0*C + c2]       = o0a / l0a;
    out[(size_t)p0*C + c2 + 1]   = o1a / l1a;
    out[(size_t)(p0+1)*C + c2]     = o0b / l0b;
    out[(size_t)(p0+1)*C + c2 + 1] = o1b / l1b;
}

// ---------------------------------------------------------------------------
extern "C" void kernel_launch(void* const* d_in, const int* in_sizes, int n_in,
                              void* d_out, int out_size, void* d_ws, size_t ws_size,
                              hipStream_t stream)
{
    const float* x    = (const float*)d_in[0];
    const float* pos  = (const float*)d_in[1];
    const float* Wq   = (const float*)d_in[2];
    const float* bq   = (const float*)d_in[3];
    const float* Wk   = (const float*)d_in[4];
    const float* bk   = (const float*)d_in[5];
    const float* Wv   = (const float*)d_in[6];
    const float* bv   = (const float*)d_in[7];
    const float* pW1  = (const float*)d_in[8];
    const float* pb1  = (const float*)d_in[9];
    const float* pg1  = (const float*)d_in[10];
    const float* pbe1 = (const float*)d_in[11];
    const float* pW2  = (const float*)d_in[12];
    const float* pb2  = (const float*)d_in[13];
    const float* pg2  = (const float*)d_in[14];
    const float* pbe2 = (const float*)d_in[15];
    const float* aW1  = (const float*)d_in[16];
    const float* ab1  = (const float*)d_in[17];
    const float* ag1  = (const float*)d_in[18];
    const float* abe1 = (const float*)d_in[19];
    const float* aW2  = (const float*)d_in[20];
    const float* ab2  = (const float*)d_in[21];
    const float* ag2  = (const float*)d_in[22];
    const float* abe2 = (const float*)d_in[23];
    const int* fps_idx = (const int*)d_in[24];
    float* out = (float*)d_out;

    char* ws = (char*)d_ws;
    size_t off = 0;
    auto alloc = [&](size_t bytes) -> void* {
        void* r = ws + off;
        off = (off + bytes + 255) & ~(size_t)255;
        return r;
    };
    float* gacc    = (float*)alloc(160*68*4);        // zeroed
    float* posmom  = (float*)alloc(8*9*4);           // zeroed
    float* stats32 = (float*)alloc(3*32*256*4);      // zeroed
    size_t zero_bytes = off;
    float* w3  = (float*)alloc(4*128*4);
    float* CqT = (float*)alloc(64*128*4);
    float* CkT = (float*)alloc(64*128*4);
    float* dq  = (float*)alloc(128*4);
    float* dk  = (float*)alloc(128*4);
    float* WvT = (float*)alloc(64*128*4);
    u16* Wb0   = (u16*)alloc(128*128*2);
    u16* Wb1   = (u16*)alloc(128*128*2);
    u16* Wb2   = (u16*)alloc(128*128*2);
    float* Aq2 = (float*)alloc((size_t)N_*128*4);
    float* Ak2 = (float*)alloc(160*128*4);
    float* xv  = (float*)alloc(160*128*4);
    u16* bigA  = (u16*)alloc((size_t)E_*128*2);      // z2
    u16* bigB  = (u16*)alloc((size_t)E_*128*2);      // za1 -> za2 (in place)

    hipMemsetAsync(d_ws, 0, zero_bytes, stream);

    prep_weights<<<69, 256, 0, stream>>>(Wq, bq, Wk, bk, aW1, ab1, pW2, aW2, Wv,
                                         CqT, CkT, dq, dk, WvT, Wb0, Wb1, Wb2);
    knn_scatter<<<256, 256, 0, stream>>>(pos, x, fps_idx, gacc, posmom);
    proj_m<<<160, 128, 0, stream>>>(gacc, CkT, dk, WvT, bv, Ak2, xv);
    bn1_prep<<<1, 256, 0, stream>>>(gacc, posmom, pW1, pb1, pg1, pbe1, w3);
    proj_q<<<N_/8, 256, 0, stream>>>(x, CqT, dq, Aq2);

    float* stA = stats32;
    float* stB = stats32 + 32*256;
    float* stC = stats32 + 2*32*256;

    // gemm1: rel -> z2 (bias pb2), stats -> stA
    gemm_fused<0><<<E_/128, 256, 0, stream>>>(nullptr, bigA, Wb0,
        nullptr, nullptr, nullptr, w3, pb2, nullptr, nullptr, pos, gacc, stA);

    // gemm2: z2 -> za1 (+Aq2-Ak2), BN2 inline from stA, stats -> stB
    gemm_fused<1><<<E_/128, 256, 0, stream>>>(bigA, bigB, Wb1,
        stA, pg2, pbe2, nullptr, nullptr, Aq2, Ak2, nullptr, nullptr, stB);

    // gemm3: za1 -> za2 in place (bias ab2), BN3 inline from stB, stats -> stC
    gemm_fused<2><<<E_/128, 256, 0, stream>>>(bigB, bigB, Wb2,
        stB, ag1, abe1, nullptr, ab2, nullptr, nullptr, nullptr, nullptr, stC);

    // final: BN2 (stA) for delta, BN4 (stC) for alpha
    final_kernel<<<N_/8, 256, 0, stream>>>(bigA, bigB,
        stA, pg2, pbe2, stC, ag2, abe2, xv, out);
}

// Round 12
// 311.956 us; speedup vs baseline: 1.5743x; 1.0058x over previous
//
#include <hip/hip_runtime.h>
#include <hip/hip_bf16.h>
#include <stdint.h>

#define B_ 8
#define P_ 2048
#define K_ 20
#define N_ (B_*P_)     // 16384
#define M_ (B_*K_)     // 160
#define C 128
#define E_ (N_*K_)     // 327680
#define EPS_ 1e-5f

typedef unsigned short u16;
typedef unsigned int u32;
typedef __attribute__((ext_vector_type(8))) short short8;
typedef __attribute__((ext_vector_type(4))) float floatx4;

__device__ __forceinline__ float bf2f(u16 u){
    union { u32 i; float f; } v; v.i = ((u32)u) << 16; return v.f;
}
__device__ __forceinline__ u16 f2bf(float f){
    union { float f; u32 i; } v; v.f = f;
    u32 r = ((v.i >> 16) & 1u) + 0x7fffu;
    return (u16)((v.i + r) >> 16);
}
__device__ __forceinline__ u32 pkbf(float a, float b){
    union { __hip_bfloat162 h; u32 u; } cv;
    cv.h = __float22bfloat162_rn(make_float2(a, b));
    return cv.u;
}

// ---------------------------------------------------------------------------
// prep: CqT = (aW1@Wq)^T [64,128], CkT = (aW1@Wk)^T, dq = aW1@bq + ab1,
//       dk = aW1@bk, WvT [64,128], frag-major bf16 copies of pW2, aW1, aW2.
// PERMUTED tiles: B-tile ct, colidx Ls holds output channel Ls*8+ct, so each
// lane's 8 accumulators are 8 consecutive channels (16B stores).
// grid 69 x 256
__global__ __launch_bounds__(256)
void prep_weights(const float* __restrict__ Wq, const float* __restrict__ bq,
                  const float* __restrict__ Wk, const float* __restrict__ bk,
                  const float* __restrict__ aW1, const float* __restrict__ ab1,
                  const float* __restrict__ pW2, const float* __restrict__ aW2,
                  const float* __restrict__ Wv,
                  float* __restrict__ CqT, float* __restrict__ CkT,
                  float* __restrict__ dq, float* __restrict__ dk,
                  float* __restrict__ WvT,
                  u16* __restrict__ Wb0, u16* __restrict__ Wb1, u16* __restrict__ Wb2)
{
    int tid = threadIdx.x, blk = blockIdx.x;
    if (blk < 32) {
        int idx = blk*256 + tid; int o = idx >> 6, i = idx & 63;
        float s = 0.f;
        for (int cc = 0; cc < 128; ++cc) s = fmaf(aW1[o*128+cc], Wq[cc*64+i], s);
        CqT[i*128 + o] = s;
    } else if (blk < 64) {
        int idx = (blk-32)*256 + tid; int o = idx >> 6, i = idx & 63;
        float s = 0.f;
        for (int cc = 0; cc < 128; ++cc) s = fmaf(aW1[o*128+cc], Wk[cc*64+i], s);
        CkT[i*128 + o] = s;
    } else if (blk == 64) {
        if (tid < 128) {
            float s = ab1[tid];
            for (int cc = 0; cc < 128; ++cc) s = fmaf(aW1[tid*128+cc], bq[cc], s);
            dq[tid] = s;
        } else {
            int o = tid - 128;
            float s = 0.f;
            for (int cc = 0; cc < 128; ++cc) s = fmaf(aW1[o*128+cc], bk[cc], s);
            dk[o] = s;
        }
    } else if (blk == 68) {
        for (int idx = tid; idx < 8192; idx += 256) {
            int o = idx >> 6, i = idx & 63;
            WvT[i*128 + o] = Wv[idx];
        }
    } else {
        // frag-major remap: slot s = (ct*4+ks)*64 + lane, 8 u16 per slot.
        // PERMUTED: frag element j = W[Ls*8 + ct][ks*32 + (lane>>4)*8 + j]
        const float* src = (blk == 65) ? pW2 : (blk == 66) ? aW1 : aW2;
        u16* dst = (blk == 65) ? Wb0 : (blk == 66) ? Wb1 : Wb2;
        for (int s = tid; s < 2048; s += 256) {
            int ln = s & 63, ks = (s >> 6) & 3, ct = s >> 8;
            int Ls = ln & 15, qs = ln >> 4;
            const float* sp = src + (Ls*8 + ct)*C + ks*32 + qs*8;
            #pragma unroll
            for (int j = 0; j < 8; ++j) dst[s*8+j] = f2bf(sp[j]);
        }
    }
}

// ---------------------------------------------------------------------------
// knn + kernel-weighted scatter into gacc[m][68] + per-graph pos moments.
// grid 256 x 256
__global__ __launch_bounds__(256)
void knn_scatter(const float* __restrict__ pos, const float* __restrict__ x,
                 const int* __restrict__ fps_idx, float* __restrict__ gacc,
                 float* __restrict__ posmom)
{
    __shared__ float fpos[K_][3];
    __shared__ float accL[K_*68];
    __shared__ int   skb[64];
    __shared__ float sek[64];
    int tid = threadIdx.x;
    int b = blockIdx.x >> 5;              // 32 blocks per graph
    if (tid < K_*3) {
        int k = tid / 3, d = tid - k*3;
        fpos[k][d] = pos[fps_idx[b*K_+k]*3 + d];
    }
    for (int i = tid; i < K_*68; i += 256) accL[i] = 0.f;
    __syncthreads();

    int wbase = blockIdx.x*64;
    if (tid < 64) {
        int p = wbase + tid;
        float px = pos[p*3], py = pos[p*3+1], pz = pos[p*3+2];
        float best = 1e30f; int kb = 0;
        #pragma unroll
        for (int k = 0; k < K_; ++k) {
            float dx = px - fpos[k][0], dy = py - fpos[k][1], dz = pz - fpos[k][2];
            float d2 = dx*dx + dy*dy + dz*dz;
            if (d2 < best) { best = d2; kb = k; }   // strict <: argmin keeps first
        }
        float ek = 1.0f / (1.0f + 5.0f*best);
        skb[tid] = kb; sek[tid] = ek;
        atomicAdd(&accL[kb*68 + 0], 1.0f);
        atomicAdd(&accL[kb*68 + 1], ek*px);
        atomicAdd(&accL[kb*68 + 2], ek*py);
        atomicAdd(&accL[kb*68 + 3], ek*pz);

        float mom[9] = {px,py,pz, px*px,px*py,px*pz, py*py,py*pz, pz*pz};
        #pragma unroll
        for (int i = 0; i < 9; ++i) {
            float v = mom[i];
            v += __shfl_xor(v,32); v += __shfl_xor(v,16); v += __shfl_xor(v,8);
            v += __shfl_xor(v,4);  v += __shfl_xor(v,2);  v += __shfl_xor(v,1);
            mom[i] = v;
        }
        if (tid == 0) {
            #pragma unroll
            for (int i = 0; i < 9; ++i) atomicAdd(&posmom[b*9+i], mom[i]);
        }
    }
    __syncthreads();

    int w = tid >> 6, lane = tid & 63;
    #pragma unroll
    for (int jj = 0; jj < 16; ++jj) {
        int j = w*16 + jj;
        int   kbj = skb[j];
        float ekj = sek[j];
        float xvv = x[(size_t)(wbase+j)*64 + lane];
        atomicAdd(&accL[kbj*68 + 4 + lane], ekj*xvv);
    }
    __syncthreads();
    for (int i = tid; i < K_*68; i += 256)
        atomicAdd(&gacc[b*K_*68 + i], accL[i]);
}

// ---------------------------------------------------------------------------
// proj_m + fps divide: divides gacc row m in place (for bn1_prep & gemm1),
// then Ak2[m] = Ck@fps_x + dk ; xv[m] = Wv@fps_x + bv. grid 160 x 128
__global__ __launch_bounds__(128)
void proj_m(float* __restrict__ gacc, const float* __restrict__ CkT,
            const float* __restrict__ dk, const float* __restrict__ WvT,
            const float* __restrict__ bv, float* __restrict__ Ak2,
            float* __restrict__ xv)
{
    __shared__ float sfx[68];
    int m = blockIdx.x, o = threadIdx.x;
    if (o < 68) {
        float c = gacc[m*68];
        float inv = 1.0f / (c > 1.f ? c : 1.f);
        float vdiv = (o >= 1) ? gacc[m*68+o]*inv : c;
        sfx[o] = vdiv;
        if (o >= 1) gacc[m*68+o] = vdiv;
    }
    __syncthreads();
    float a = dk[o], v = bv[o];
    for (int i = 0; i < 64; ++i) {
        float xi = sfx[4+i];
        a = fmaf(CkT[i*128+o], xi, a);
        v = fmaf(WvT[i*128+o], xi, v);
    }
    Ak2[m*C+o] = a; xv[m*C+o] = v;
}

// ---------------------------------------------------------------------------
// closed-form BN1 stats from rel moments; fold BN1+pW1 -> w3[4][128].
// reads DIVIDED gacc (proj_m runs first). single block x 256
__global__ __launch_bounds__(256)
void bn1_prep(const float* __restrict__ gacc, const float* __restrict__ posmom,
              const float* __restrict__ pW1, const float* __restrict__ pb1,
              const float* __restrict__ pg1, const float* __restrict__ pbe1,
              float* __restrict__ w3)
{
    __shared__ float sF[8][3], sG[8][6];
    __shared__ float S1[3], S2[6];
    int t = threadIdx.x;
    if (t < 8) {
        float F0=0,F1=0,F2=0,G0=0,G1=0,G2=0,G3=0,G4=0,G5=0;
        for (int k = 0; k < K_; ++k) {
            const float* f = gacc + (t*K_+k)*68 + 1;
            float x=f[0], y=f[1], z=f[2];
            F0+=x; F1+=y; F2+=z;
            G0+=x*x; G1+=x*y; G2+=x*z; G3+=y*y; G4+=y*z; G5+=z*z;
        }
        sF[t][0]=F0; sF[t][1]=F1; sF[t][2]=F2;
        sG[t][0]=G0; sG[t][1]=G1; sG[t][2]=G2; sG[t][3]=G3; sG[t][4]=G4; sG[t][5]=G5;
    }
    __syncthreads();
    if (t == 0) {
        float s1[3]={0,0,0}, s2[6]={0,0,0,0,0,0};
        for (int b = 0; b < 8; ++b) {
            const float* pm = posmom + b*9;
            float Ax=pm[0],Ay=pm[1],Az=pm[2];
            float Fx=sF[b][0],Fy=sF[b][1],Fz=sF[b][2];
            s1[0] += (float)K_*Ax - (float)P_*Fx;
            s1[1] += (float)K_*Ay - (float)P_*Fy;
            s1[2] += (float)K_*Az - (float)P_*Fz;
            s2[0] += (float)K_*pm[3] - 2.f*Ax*Fx + (float)P_*sG[b][0];
            s2[1] += (float)K_*pm[4] - Ax*Fy - Ay*Fx + (float)P_*sG[b][1];
            s2[2] += (float)K_*pm[5] - Ax*Fz - Az*Fx + (float)P_*sG[b][2];
            s2[3] += (float)K_*pm[6] - 2.f*Ay*Fy + (float)P_*sG[b][3];
            s2[4] += (float)K_*pm[7] - Ay*Fz - Az*Fy + (float)P_*sG[b][4];
            s2[5] += (float)K_*pm[8] - 2.f*Az*Fz + (float)P_*sG[b][5];
        }
        for (int i = 0; i < 3; ++i) S1[i] = s1[i];
        for (int i = 0; i < 6; ++i) S2[i] = s2[i];
    }
    __syncthreads();
    if (t < 128) {
        float w0=pW1[t*3], w1=pW1[t*3+1], w2=pW1[t*3+2], bb=pb1[t];
        float wS1 = w0*S1[0] + w1*S1[1] + w2*S1[2];
        float wS2w = w0*w0*S2[0] + w1*w1*S2[3] + w2*w2*S2[5]
                   + 2.f*(w0*w1*S2[1] + w0*w2*S2[2] + w1*w2*S2[4]);
        const float invE = 1.0f/(float)E_;
        float m1  = wS1*invE + bb;
        float Ez2 = (wS2w + 2.f*bb*wS1)*invE + bb*bb;
        float var = Ez2 - m1*m1;
        float sc = pg1[t] * rsqrtf(var + EPS_);
        float sh = pbe1[t] - m1*sc;
        w3[0*128+t] = w0*sc; w3[1*128+t] = w1*sc;
        w3[2*128+t] = w2*sc; w3[3*128+t] = bb*sc + sh;
    }
}

// Aq2[p] = CqT^T@x[p] + dq. 8 points/block. grid 2048 x 256
__global__ __launch_bounds__(256)
void proj_q(const float* __restrict__ x, const float* __restrict__ CqT,
            const float* __restrict__ dq, float* __restrict__ Aq2)
{
    __shared__ float xs[512];
    int tid = threadIdx.x;
    int p0 = blockIdx.x*8;
    const float* xp = x + (size_t)p0*64;
    for (int i = tid; i < 512; i += 256) xs[i] = xp[i];
    __syncthreads();
    int g = tid >> 7, o = tid & 127;
    const float* xb = xs + g*256;
    float d = dq[o];
    float a0=d, a1=d, a2=d, a3=d;
    #pragma unroll 4
    for (int i = 0; i < 64; ++i) {
        float w = CqT[i*128 + o];
        a0 = fmaf(w, xb[i],       a0);
        a1 = fmaf(w, xb[64+i],    a1);
        a2 = fmaf(w, xb[128+i],   a2);
        a3 = fmaf(w, xb[192+i],   a3);
    }
    int pb = p0 + g*4;
    Aq2[(size_t)(pb+0)*C + o] = a0;
    Aq2[(size_t)(pb+1)*C + o] = a1;
    Aq2[(size_t)(pb+2)*C + o] = a2;
    Aq2[(size_t)(pb+3)*C + o] = a3;
}

// ---------------------------------------------------------------------------
// Fused GEMM v8: B staged in LDS once per block (straight 32KB copy of the
// frag-major global image; ds_read_b128 lane-contiguous = conflict-free).
// Moves ~335 MB of per-wave B re-reads off the VMEM/L2 pipe onto the idle
// LDS pipe; K-loop VMEM instrs drop 40 -> 8 per wave.
// Permuted output tiles -> lane owns 8 consecutive channels => 16B stores.
// MODE 0: A = BN1-folded pos-MLP layer1 on the fly; +bias(pb2); store z2
// MODE 1: A = relu(zin*sc+sh) [BN from statsin]; +Aq2[p]-Ak2[m]; store za1
// MODE 2: A = relu(zin*sc+sh) [BN from statsin]; +bias(ab2); store za2
// grid 2560 x 256
template<int MODE>
__global__ __launch_bounds__(256)
void gemm_fused(const u16* __restrict__ zin, u16* __restrict__ zout,
                const u16* __restrict__ Wbf,
                const float* __restrict__ statsin, const float* __restrict__ g,
                const float* __restrict__ be,
                const float* __restrict__ w3, const float* __restrict__ bias,
                const float* __restrict__ rowq, const float* __restrict__ rowk,
                const float* __restrict__ pos, const float* __restrict__ gacc,
                float* __restrict__ stats32)
{
    __shared__ short8 sB[2048];         // 32 KB frag-major B image
    __shared__ float s_stat[2][C];
    __shared__ float saff[5*C];

    int tid = threadIdx.x;
    const int wave = tid >> 6, lane = tid & 63;
    const int L = lane & 15, q = lane >> 4;

    // stage B (global frag-major layout == LDS slot order)
    for (int s = tid; s < 2048; s += 256)
        sB[s] = *(const short8*)(Wbf + (size_t)s*8);

    ((float*)s_stat)[tid] = 0.f;
    if constexpr (MODE == 0) {
        for (int i = tid; i < 512; i += 256) saff[i] = w3[i];
        if (tid < C) saff[512+tid] = bias[tid];
    } else {
        if (tid < C) {
            float s = 0.f, sq = 0.f;
            for (int r = 0; r < 32; ++r) {
                s  += statsin[r*256 + tid];
                sq += statsin[r*256 + 128 + tid];
            }
            float mean = s*(1.0f/E_), var = sq*(1.0f/E_) - mean*mean;
            float sc = g[tid] * rsqrtf(var + EPS_);
            saff[tid] = sc; saff[C+tid] = be[tid] - mean*sc;
        }
        if constexpr (MODE == 2) {
            if (tid >= 128) saff[2*C + tid - 128] = bias[tid - 128];
        }
    }
    __syncthreads();

    int tbs[2];
    tbs[0] = (blockIdx.x*8 + wave)*16;
    tbs[1] = (blockIdx.x*8 + wave + 4)*16;

    short8 An[2][4];
    float rr0[2], rr1[2], rr2[2];
    #pragma unroll
    for (int tt = 0; tt < 2; ++tt) {
        if constexpr (MODE != 0) {
            const u16* ap = zin + (size_t)(tbs[tt] + L)*C + q*8;
            An[tt][0] = *(const short8*)ap;
            An[tt][1] = *(const short8*)(ap + 32);
            An[tt][2] = *(const short8*)(ap + 64);
            An[tt][3] = *(const short8*)(ap + 96);
        } else {
            unsigned e = (unsigned)(tbs[tt] + L);
            unsigned p = e / 20u; int k = (int)(e - p*20u);
            int m = (int)(p >> 11)*20 + k;
            const float* fp = gacc + m*68 + 1;
            rr0[tt] = pos[p*3]   - fp[0];
            rr1[tt] = pos[p*3+1] - fp[1];
            rr2[tt] = pos[p*3+2] - fp[2];
        }
    }

    floatx4 acc[2][8];
    #pragma unroll
    for (int tt = 0; tt < 2; ++tt)
        #pragma unroll
        for (int ct = 0; ct < 8; ++ct) acc[tt][ct] = (floatx4){0.f,0.f,0.f,0.f};

    #pragma unroll
    for (int ks = 0; ks < 4; ++ks) {
        int ch0 = ks*32 + q*8;
        short8 bfr[8];
        #pragma unroll
        for (int ct = 0; ct < 8; ++ct)
            bfr[ct] = sB[(ct*4+ks)*64 + lane];
        #pragma unroll
        for (int tt = 0; tt < 2; ++tt) {
            union { short8 s8; u32 u[4]; } af;
            if constexpr (MODE == 0) {
                #pragma unroll
                for (int jj = 0; jj < 4; ++jj) {
                    int c0 = ch0 + jj*2, c1 = ch0 + jj*2 + 1;
                    float f0 = fmaf(saff[c0], rr0[tt], fmaf(saff[C+c0], rr1[tt],
                               fmaf(saff[2*C+c0], rr2[tt], saff[3*C+c0])));
                    float f1 = fmaf(saff[c1], rr0[tt], fmaf(saff[C+c1], rr1[tt],
                               fmaf(saff[2*C+c1], rr2[tt], saff[3*C+c1])));
                    f0 = f0 > 0.f ? f0 : 0.f;
                    f1 = f1 > 0.f ? f1 : 0.f;
                    af.u[jj] = pkbf(f0, f1);
                }
            } else {
                short8 ar = An[tt][ks];
                #pragma unroll
                for (int jj = 0; jj < 4; ++jj) {
                    int c0 = ch0 + jj*2, c1 = ch0 + jj*2 + 1;
                    float f0 = fmaf(bf2f((u16)ar[jj*2]),   saff[c0], saff[C+c0]);
                    float f1 = fmaf(bf2f((u16)ar[jj*2+1]), saff[c1], saff[C+c1]);
                    f0 = f0 > 0.f ? f0 : 0.f;
                    f1 = f1 > 0.f ? f1 : 0.f;
                    af.u[jj] = pkbf(f0, f1);
                }
            }
            // acc[tt][j] holds output channel L*8 + j (permuted B tiles)
            #pragma unroll
            for (int ct = 0; ct < 8; ++ct)
                acc[tt][ct] = __builtin_amdgcn_mfma_f32_16x16x32_bf16(af.s8, bfr[ct], acc[tt][ct], 0, 0, 0);
        }
    }

    float ssum[8], ssq[8];
    #pragma unroll
    for (int i = 0; i < 8; ++i) { ssum[i] = 0.f; ssq[i] = 0.f; }

    #pragma unroll
    for (int tt = 0; tt < 2; ++tt) {
        const int tilebase = tbs[tt];
        int pp[4], mm[4];
        if constexpr (MODE == 1) {
            #pragma unroll
            for (int r = 0; r < 4; ++r) {
                unsigned e2 = (unsigned)(tilebase + q*4 + r);
                unsigned p2 = e2 / 20u; int k2 = (int)(e2 - p2*20u);
                pp[r] = (int)p2; mm[r] = (int)(p2 >> 11)*20 + k2;
            }
        }
        u16* orow = zout + (size_t)(tilebase + q*4)*C + L*8;
        floatx4 bb0, bb1;
        if constexpr (MODE == 0) {
            bb0 = *(const floatx4*)&saff[4*C + L*8];
            bb1 = *(const floatx4*)&saff[4*C + L*8 + 4];
        } else if constexpr (MODE == 2) {
            bb0 = *(const floatx4*)&saff[2*C + L*8];
            bb1 = *(const floatx4*)&saff[2*C + L*8 + 4];
        }
        #pragma unroll
        for (int r = 0; r < 4; ++r) {
            floatx4 z0, z1;
            #pragma unroll
            for (int j = 0; j < 4; ++j) { z0[j] = acc[tt][j][r]; z1[j] = acc[tt][4+j][r]; }
            if constexpr (MODE == 0 || MODE == 2) { z0 += bb0; z1 += bb1; }
            if constexpr (MODE == 1) {
                const float* rq = &rowq[pp[r]*C + L*8];
                const float* rk = &rowk[mm[r]*C + L*8];
                z0 += *(const floatx4*)rq - *(const floatx4*)rk;
                z1 += *(const floatx4*)(rq+4) - *(const floatx4*)(rk+4);
            }
            #pragma unroll
            for (int j = 0; j < 4; ++j) {
                ssum[j]   += z0[j]; ssq[j]   += z0[j]*z0[j];
                ssum[4+j] += z1[j]; ssq[4+j] += z1[j]*z1[j];
            }
            union { short8 s8; u32 u[4]; } ov;
            ov.u[0] = pkbf(z0[0], z0[1]);
            ov.u[1] = pkbf(z0[2], z0[3]);
            ov.u[2] = pkbf(z1[0], z1[1]);
            ov.u[3] = pkbf(z1[2], z1[3]);
            *(short8*)(orow + (size_t)r*C) = ov.s8;   // 16B store, full rows
        }
    }

    // stats: ssum[j] = channel lane*8+j partial; reduce over q-groups, then
    // the 16 L-lanes own disjoint 8-channel blocks
    #pragma unroll
    for (int j = 0; j < 8; ++j) {
        float v = ssum[j]; v += __shfl_xor(v,16); v += __shfl_xor(v,32);
        float w = ssq[j];  w += __shfl_xor(w,16); w += __shfl_xor(w,32);
        if (lane < 16) {
            atomicAdd(&s_stat[0][lane*8+j], v);
            atomicAdd(&s_stat[1][lane*8+j], w);
        }
    }
    __syncthreads();
    float* dst = stats32 + ((blockIdx.x & 31) << 8);
    atomicAdd(&dst[tid], ((float*)s_stat)[tid]);
}

// ---------------------------------------------------------------------------
// final: alpha = softmax_k(relu(BN4(za2))); delta = relu(BN2(z2));
// out[p,c] = sum_k alpha*(xv[m,c]+delta). BN2/BN4 affines reduced inline
// from raw stat replicas. 2 points per wave (independent chains, shared xv),
// 2 channels/lane, 8 points/block. grid 2048 x 256
__global__ __launch_bounds__(256)
void final_kernel(const u16* __restrict__ z2, const u16* __restrict__ za2,
                  const float* __restrict__ stA, const float* __restrict__ pg2,
                  const float* __restrict__ pbe2,
                  const float* __restrict__ stC, const float* __restrict__ ag2,
                  const float* __restrict__ abe2,
                  const float* __restrict__ xv, float* __restrict__ out)
{
    __shared__ float saff[4*C];   // sc2, sh2, sc4, sh4
    int tid = threadIdx.x;
    if (tid < C) {
        float s=0.f, sq=0.f;
        for (int r = 0; r < 32; ++r) { s += stA[r*256+tid]; sq += stA[r*256+128+tid]; }
        float mean = s*(1.0f/E_), var = sq*(1.0f/E_)-mean*mean;
        float sc = pg2[tid]*rsqrtf(var+EPS_);
        saff[tid] = sc; saff[C+tid] = pbe2[tid]-mean*sc;
    } else {
        int c = tid - C;
        float s=0.f, sq=0.f;
        for (int r = 0; r < 32; ++r) { s += stC[r*256+c]; sq += stC[r*256+128+c]; }
        float mean = s*(1.0f/E_), var = sq*(1.0f/E_)-mean*mean;
        float sc = ag2[c]*rsqrtf(var+EPS_);
        saff[2*C+c] = sc; saff[3*C+c] = abe2[c]-mean*sc;
    }
    __syncthreads();

    int wave = tid >> 6, lane = tid & 63;
    int p0 = blockIdx.x*8 + wave*2;      // two points: p0, p0+1 (same graph)
    int c2 = lane*2;
    int b = p0 >> 11;
    float S2x=saff[c2], S2y=saff[c2+1], H2x=saff[C+c2], H2y=saff[C+c2+1];
    float S4x=saff[2*C+c2], S4y=saff[2*C+c2+1], H4x=saff[3*C+c2], H4y=saff[3*C+c2+1];
    size_t eb0 = (size_t)p0 * K_;
    size_t eb1 = eb0 + K_;
    const float* xvb = xv + (size_t)(b*K_)*C + c2;
    float l0a=0.f, l1a=0.f, o0a=0.f, o1a=0.f;
    float l0b=0.f, l1b=0.f, o0b=0.f, o1b=0.f;
    #pragma unroll
    for (int k = 0; k < K_; ++k) {
        u32 waA = *(const u32*)(za2 + (eb0+k)*C + c2);
        u32 wzA = *(const u32*)(z2  + (eb0+k)*C + c2);
        u32 waB = *(const u32*)(za2 + (eb1+k)*C + c2);
        u32 wzB = *(const u32*)(z2  + (eb1+k)*C + c2);
        float2 xvv = *(const float2*)(xvb + (size_t)k*C);
        float aa0 = fmaf(bf2f((u16)(waA & 0xffffu)), S4x, H4x); aa0 = aa0 > 0.f ? aa0 : 0.f;
        float aa1 = fmaf(bf2f((u16)(waA >> 16)),     S4y, H4y); aa1 = aa1 > 0.f ? aa1 : 0.f;
        float dd0 = fmaf(bf2f((u16)(wzA & 0xffffu)), S2x, H2x); dd0 = dd0 > 0.f ? dd0 : 0.f;
        float dd1 = fmaf(bf2f((u16)(wzA >> 16)),     S2y, H2y); dd1 = dd1 > 0.f ? dd1 : 0.f;
        float e0 = __expf(aa0), e1 = __expf(aa1);
        l0a += e0; l1a += e1;
        o0a = fmaf(e0, xvv.x + dd0, o0a);
        o1a = fmaf(e1, xvv.y + dd1, o1a);
        float ba0 = fmaf(bf2f((u16)(waB & 0xffffu)), S4x, H4x); ba0 = ba0 > 0.f ? ba0 : 0.f;
        float ba1 = fmaf(bf2f((u16)(waB >> 16)),     S4y, H4y); ba1 = ba1 > 0.f ? ba1 : 0.f;
        float bd0 = fmaf(bf2f((u16)(wzB & 0xffffu)), S2x, H2x); bd0 = bd0 > 0.f ? bd0 : 0.f;
        float bd1 = fmaf(bf2f((u16)(wzB >> 16)),     S2y, H2y); bd1 = bd1 > 0.f ? bd1 : 0.f;
        float f0 = __expf(ba0), f1 = __expf(ba1);
        l0b += f0; l1b += f1;
        o0b = fmaf(f0, xvv.x + bd0, o0b);
        o1b = fmaf(f1, xvv.y + bd1, o1b);
    }
    out[(size_t)p0*C + c2]       = o0a / l0a;
    out[(size_t)p0*C + c2 + 1]   = o1a / l1a;
    out[(size_t)(p0+1)*C + c2]     = o0b / l0b;
    out[(size_t)(p0+1)*C + c2 + 1] = o1b / l1b;
}

// ---------------------------------------------------------------------------
extern "C" void kernel_launch(void* const* d_in, const int* in_sizes, int n_in,
                              void* d_out, int out_size, void* d_ws, size_t ws_size,
                              hipStream_t stream)
{
    const float* x    = (const float*)d_in[0];
    const float* pos  = (const float*)d_in[1];
    const float* Wq   = (const float*)d_in[2];
    const float* bq   = (const float*)d_in[3];
    const float* Wk   = (const float*)d_in[4];
    const float* bk   = (const float*)d_in[5];
    const float* Wv   = (const float*)d_in[6];
    const float* bv   = (const float*)d_in[7];
    const float* pW1  = (const float*)d_in[8];
    const float* pb1  = (const float*)d_in[9];
    const float* pg1  = (const float*)d_in[10];
    const float* pbe1 = (const float*)d_in[11];
    const float* pW2  = (const float*)d_in[12];
    const float* pb2  = (const float*)d_in[13];
    const float* pg2  = (const float*)d_in[14];
    const float* pbe2 = (const float*)d_in[15];
    const float* aW1  = (const float*)d_in[16];
    const float* ab1  = (const float*)d_in[17];
    const float* ag1  = (const float*)d_in[18];
    const float* abe1 = (const float*)d_in[19];
    const float* aW2  = (const float*)d_in[20];
    const float* ab2  = (const float*)d_in[21];
    const float* ag2  = (const float*)d_in[22];
    const float* abe2 = (const float*)d_in[23];
    const int* fps_idx = (const int*)d_in[24];
    float* out = (float*)d_out;

    char* ws = (char*)d_ws;
    size_t off = 0;
    auto alloc = [&](size_t bytes) -> void* {
        void* r = ws + off;
        off = (off + bytes + 255) & ~(size_t)255;
        return r;
    };
    float* gacc    = (float*)alloc(160*68*4);        // zeroed
    float* posmom  = (float*)alloc(8*9*4);           // zeroed
    float* stats32 = (float*)alloc(3*32*256*4);      // zeroed
    size_t zero_bytes = off;
    float* w3  = (float*)alloc(4*128*4);
    float* CqT = (float*)alloc(64*128*4);
    float* CkT = (float*)alloc(64*128*4);
    float* dq  = (float*)alloc(128*4);
    float* dk  = (float*)alloc(128*4);
    float* WvT = (float*)alloc(64*128*4);
    u16* Wb0   = (u16*)alloc(128*128*2);
    u16* Wb1   = (u16*)alloc(128*128*2);
    u16* Wb2   = (u16*)alloc(128*128*2);
    float* Aq2 = (float*)alloc((size_t)N_*128*4);
    float* Ak2 = (float*)alloc(160*128*4);
    float* xv  = (float*)alloc(160*128*4);
    u16* bigA  = (u16*)alloc((size_t)E_*128*2);      // z2
    u16* bigB  = (u16*)alloc((size_t)E_*128*2);      // za1 -> za2 (in place)

    hipMemsetAsync(d_ws, 0, zero_bytes, stream);

    prep_weights<<<69, 256, 0, stream>>>(Wq, bq, Wk, bk, aW1, ab1, pW2, aW2, Wv,
                                         CqT, CkT, dq, dk, WvT, Wb0, Wb1, Wb2);
    knn_scatter<<<256, 256, 0, stream>>>(pos, x, fps_idx, gacc, posmom);
    proj_m<<<160, 128, 0, stream>>>(gacc, CkT, dk, WvT, bv, Ak2, xv);
    bn1_prep<<<1, 256, 0, stream>>>(gacc, posmom, pW1, pb1, pg1, pbe1, w3);
    proj_q<<<N_/8, 256, 0, stream>>>(x, CqT, dq, Aq2);

    float* stA = stats32;
    float* stB = stats32 + 32*256;
    float* stC = stats32 + 2*32*256;

    // gemm1: rel -> z2 (bias pb2), stats -> stA
    gemm_fused<0><<<E_/128, 256, 0, stream>>>(nullptr, bigA, Wb0,
        nullptr, nullptr, nullptr, w3, pb2, nullptr, nullptr, pos, gacc, stA);

    // gemm2: z2 -> za1 (+Aq2-Ak2), BN2 inline from stA, stats -> stB
    gemm_fused<1><<<E_/128, 256, 0, stream>>>(bigA, bigB, Wb1,
        stA, pg2, pbe2, nullptr, nullptr, Aq2, Ak2, nullptr, nullptr, stB);

    // gemm3: za1 -> za2 in place (bias ab2), BN3 inline from stB, stats -> stC
    gemm_fused<2><<<E_/128, 256, 0, stream>>>(bigB, bigB, Wb2,
        stB, ag1, abe1, nullptr, ab2, nullptr, nullptr, nullptr, nullptr, stC);

    // final: BN2 (stA) for delta, BN4 (stC) for alpha
    final_kernel<<<N_/8, 256, 0, stream>>>(bigA, bigB,
        stA, pg2, pbe2, stC, ag2, abe2, xv, out);
}